// Round 1
// baseline (1012.559 us; speedup 1.0000x reference)
//
#include <hip/hip_runtime.h>
#include <cmath>

#define B_  2
#define S_  2048
#define H_  1024
#define NH_ 16
#define HD_ 64

// ---------------------------------------------------------------------------
// GEMM: C[M,N] = A[M,K] @ W[N,K]^T + bias[N]   (all fp32, row-major)
// 128x128 tile, BK=16, 256 threads, 8x8 micro-tile with split-tile mapping:
// thread (ty,tx) owns rows {ty*4+i, 64+ty*4+i} and cols {tx*4+j, 64+tx*4+j}
// so LDS reads are float4 chunks at stride-4 starts -> <=2-way bank aliasing.
// ---------------------------------------------------------------------------
__global__ __launch_bounds__(256, 2)
void sgemm_bt_bias(const float* __restrict__ A, const float* __restrict__ W,
                   const float* __restrict__ bias, float* __restrict__ C,
                   int M, int N, int K)
{
    __shared__ float As[16][128 + 4];
    __shared__ float Bs[16][128 + 4];

    const int tid = threadIdx.x;
    const int ty  = tid >> 4;   // 0..15
    const int tx  = tid & 15;   // 0..15
    const int bm  = blockIdx.x * 128;
    const int bn  = blockIdx.y * 128;

    float acc[8][8];
#pragma unroll
    for (int i = 0; i < 8; ++i)
#pragma unroll
        for (int j = 0; j < 8; ++j) acc[i][j] = 0.f;

    for (int k0 = 0; k0 < K; k0 += 16) {
#pragma unroll
        for (int i = 0; i < 2; ++i) {
            const int l  = tid + i * 256;     // 0..511
            const int r  = l >> 2;            // 0..127
            const int k4 = (l & 3) << 2;      // 0,4,8,12
            const float4 va = *reinterpret_cast<const float4*>(
                A + (size_t)(bm + r) * K + k0 + k4);
            As[k4 + 0][r] = va.x; As[k4 + 1][r] = va.y;
            As[k4 + 2][r] = va.z; As[k4 + 3][r] = va.w;
            const float4 vb = *reinterpret_cast<const float4*>(
                W + (size_t)(bn + r) * K + k0 + k4);
            Bs[k4 + 0][r] = vb.x; Bs[k4 + 1][r] = vb.y;
            Bs[k4 + 2][r] = vb.z; Bs[k4 + 3][r] = vb.w;
        }
        __syncthreads();
#pragma unroll
        for (int kk = 0; kk < 16; ++kk) {
            float a[8], b[8];
            *reinterpret_cast<float4*>(&a[0]) =
                *reinterpret_cast<const float4*>(&As[kk][ty * 4]);
            *reinterpret_cast<float4*>(&a[4]) =
                *reinterpret_cast<const float4*>(&As[kk][64 + ty * 4]);
            *reinterpret_cast<float4*>(&b[0]) =
                *reinterpret_cast<const float4*>(&Bs[kk][tx * 4]);
            *reinterpret_cast<float4*>(&b[4]) =
                *reinterpret_cast<const float4*>(&Bs[kk][64 + tx * 4]);
#pragma unroll
            for (int i = 0; i < 8; ++i)
#pragma unroll
                for (int j = 0; j < 8; ++j)
                    acc[i][j] = fmaf(a[i], b[j], acc[i][j]);
        }
        __syncthreads();
    }

    float bj[8];
#pragma unroll
    for (int j = 0; j < 8; ++j) {
        const int col = bn + ((j < 4) ? (tx * 4 + j) : (64 + tx * 4 + (j - 4)));
        bj[j] = bias[col];
    }
#pragma unroll
    for (int i = 0; i < 8; ++i) {
        const int row = bm + ((i < 4) ? (ty * 4 + i) : (64 + ty * 4 + (i - 4)));
        float4 o0, o1;
        o0.x = acc[i][0] + bj[0]; o0.y = acc[i][1] + bj[1];
        o0.z = acc[i][2] + bj[2]; o0.w = acc[i][3] + bj[3];
        o1.x = acc[i][4] + bj[4]; o1.y = acc[i][5] + bj[5];
        o1.z = acc[i][6] + bj[6]; o1.w = acc[i][7] + bj[7];
        *reinterpret_cast<float4*>(C + (size_t)row * N + bn + tx * 4)      = o0;
        *reinterpret_cast<float4*>(C + (size_t)row * N + bn + 64 + tx * 4) = o1;
    }
}

// ---------------------------------------------------------------------------
// Flash-style attention, fp32. One block per (q-tile of 64, head, batch).
// 256 threads as 16x16; thread (ty,tx): rows r=ty*4..+3 of the q-tile,
// score cols c=tx*4..+3 / output dims d=tx*4..+3. P staged via LDS for PV.
// qkv layout: [B*S][3H] rows; q cols h*64.., k cols 1024+h*64, v 2048+h*64.
// av output: [B*S][H] with col h*64+d  (== 'bqhd' reshape).
// ---------------------------------------------------------------------------
__global__ __launch_bounds__(256, 2)
void attn_fwd(const float* __restrict__ qkv, const float* __restrict__ mask,
              float* __restrict__ av)
{
    __shared__ float Qt[64][68];   // [d][r]
    __shared__ float Kt[64][68];   // [d][c]
    __shared__ float Vs[64][68];   // [c][d]
    __shared__ float Pt[64][68];   // [c][r]

    const int tid = threadIdx.x;
    const int ty  = tid >> 4;
    const int tx  = tid & 15;
    const int qt  = blockIdx.x;    // 0..31
    const int h   = blockIdx.y;    // 0..15
    const int b   = blockIdx.z;    // 0..1

    const size_t rs = 3 * H_;      // qkv row stride
    const float* Qg = qkv + ((size_t)b * S_ + qt * 64) * rs + h * HD_;
    const float* Kg = qkv + ((size_t)b * S_) * rs + H_ + h * HD_;
    const float* Vg = Kg + H_;

    // Q tile -> LDS transposed (once)
#pragma unroll
    for (int i = 0; i < 4; ++i) {
        const int l  = tid + i * 256;
        const int r  = l >> 4;          // 0..63
        const int d4 = (l & 15) << 2;   // 0,4,..,60
        const float4 v = *reinterpret_cast<const float4*>(Qg + (size_t)r * rs + d4);
        Qt[d4 + 0][r] = v.x; Qt[d4 + 1][r] = v.y;
        Qt[d4 + 2][r] = v.z; Qt[d4 + 3][r] = v.w;
    }

    float m_r[4], l_r[4], o[4][4];
#pragma unroll
    for (int i = 0; i < 4; ++i) {
        m_r[i] = -INFINITY; l_r[i] = 0.f;
#pragma unroll
        for (int j = 0; j < 4; ++j) o[i][j] = 0.f;
    }

    for (int kt = 0; kt < S_ / 64; ++kt) {
        __syncthreads();   // prev PV (and Q load) complete before overwriting K/V
#pragma unroll
        for (int i = 0; i < 4; ++i) {
            const int l  = tid + i * 256;
            const int r  = l >> 4;
            const int d4 = (l & 15) << 2;
            const size_t g = (size_t)(kt * 64 + r) * rs + d4;
            const float4 kv = *reinterpret_cast<const float4*>(Kg + g);
            Kt[d4 + 0][r] = kv.x; Kt[d4 + 1][r] = kv.y;
            Kt[d4 + 2][r] = kv.z; Kt[d4 + 3][r] = kv.w;
            const float4 vv = *reinterpret_cast<const float4*>(Vg + g);
            *reinterpret_cast<float4*>(&Vs[r][d4]) = vv;
        }
        __syncthreads();

        // S = Q K^T for this tile
        float s[4][4];
#pragma unroll
        for (int i = 0; i < 4; ++i)
#pragma unroll
            for (int j = 0; j < 4; ++j) s[i][j] = 0.f;
#pragma unroll 16
        for (int d = 0; d < HD_; ++d) {
            const float4 qv = *reinterpret_cast<const float4*>(&Qt[d][ty * 4]);
            const float4 kv = *reinterpret_cast<const float4*>(&Kt[d][tx * 4]);
            const float q_[4] = {qv.x, qv.y, qv.z, qv.w};
            const float k_[4] = {kv.x, kv.y, kv.z, kv.w};
#pragma unroll
            for (int i = 0; i < 4; ++i)
#pragma unroll
                for (int j = 0; j < 4; ++j)
                    s[i][j] = fmaf(q_[i], k_[j], s[i][j]);
        }
        // (dot + mask[col]) * 1/sqrt(64)
        float mcol[4];
#pragma unroll
        for (int j = 0; j < 4; ++j) mcol[j] = mask[kt * 64 + tx * 4 + j];
#pragma unroll
        for (int i = 0; i < 4; ++i)
#pragma unroll
            for (int j = 0; j < 4; ++j)
                s[i][j] = (s[i][j] + mcol[j]) * 0.125f;

        // online softmax (row stats shared by the 16 tx-lanes of each ty)
#pragma unroll
        for (int i = 0; i < 4; ++i) {
            float mx = fmaxf(fmaxf(s[i][0], s[i][1]), fmaxf(s[i][2], s[i][3]));
#pragma unroll
            for (int off = 1; off < 16; off <<= 1)
                mx = fmaxf(mx, __shfl_xor(mx, off));
            const float mnew = fmaxf(m_r[i], mx);
            const float corr = __expf(m_r[i] - mnew);
            float ps = 0.f;
#pragma unroll
            for (int j = 0; j < 4; ++j) {
                s[i][j] = __expf(s[i][j] - mnew);
                ps += s[i][j];
            }
#pragma unroll
            for (int off = 1; off < 16; off <<= 1)
                ps += __shfl_xor(ps, off);
            l_r[i] = l_r[i] * corr + ps;
            m_r[i] = mnew;
#pragma unroll
            for (int j = 0; j < 4; ++j) o[i][j] *= corr;
        }

        // stage P^T
#pragma unroll
        for (int i = 0; i < 4; ++i)
#pragma unroll
            for (int j = 0; j < 4; ++j)
                Pt[tx * 4 + j][ty * 4 + i] = s[i][j];
        __syncthreads();

        // O += P V
#pragma unroll 16
        for (int c = 0; c < 64; ++c) {
            const float4 pv = *reinterpret_cast<const float4*>(&Pt[c][ty * 4]);
            const float4 vv = *reinterpret_cast<const float4*>(&Vs[c][tx * 4]);
            const float p_[4] = {pv.x, pv.y, pv.z, pv.w};
            const float v_[4] = {vv.x, vv.y, vv.z, vv.w};
#pragma unroll
            for (int i = 0; i < 4; ++i)
#pragma unroll
                for (int j = 0; j < 4; ++j)
                    o[i][j] = fmaf(p_[i], v_[j], o[i][j]);
        }
    }

    // normalize + write av
#pragma unroll
    for (int i = 0; i < 4; ++i) {
        const float inv = 1.f / l_r[i];
        const int row = b * S_ + qt * 64 + ty * 4 + i;
        float4 ov;
        ov.x = o[i][0] * inv; ov.y = o[i][1] * inv;
        ov.z = o[i][2] * inv; ov.w = o[i][3] * inv;
        *reinterpret_cast<float4*>(av + (size_t)row * H_ + h * HD_ + tx * 4) = ov;
    }
}

// ---------------------------------------------------------------------------
extern "C" void kernel_launch(void* const* d_in, const int* in_sizes, int n_in,
                              void* d_out, int out_size, void* d_ws, size_t ws_size,
                              hipStream_t stream)
{
    const float* x     = (const float*)d_in[0];
    const float* mask  = (const float*)d_in[1];
    const float* w_qkv = (const float*)d_in[2];
    const float* b_qkv = (const float*)d_in[3];
    const float* w_o   = (const float*)d_in[4];
    const float* b_o   = (const float*)d_in[5];
    float* out = (float*)d_out;

    float* qkv = (float*)d_ws;                          // [4096][3072] = 48 MB
    float* av  = qkv + (size_t)B_ * S_ * 3 * H_;        // [4096][1024] = 16 MB

    const dim3 blk(256);
    // QKV projection: M=4096, N=3072, K=1024
    sgemm_bt_bias<<<dim3(32, 24), blk, 0, stream>>>(x, w_qkv, b_qkv, qkv,
                                                    B_ * S_, 3 * H_, H_);
    // attention: one block per (q-tile, head, batch)
    attn_fwd<<<dim3(S_ / 64, NH_, B_), blk, 0, stream>>>(qkv, mask, av);
    // output projection: M=4096, N=1024, K=1024
    sgemm_bt_bias<<<dim3(32, 8), blk, 0, stream>>>(av, w_o, b_o, out,
                                                   B_ * S_, H_, H_);
}

// Round 2
// 626.955 us; speedup vs baseline: 1.6150x; 1.6150x over previous
//
#include <hip/hip_runtime.h>
#include <cmath>

#define B_  2
#define S_  2048
#define H_  1024
#define NH_ 16
#define HD_ 64

typedef _Float16 half8  __attribute__((ext_vector_type(8)));
typedef _Float16 half4v __attribute__((ext_vector_type(4)));
typedef float    f32x16 __attribute__((ext_vector_type(16)));

#define MFMA32(a, b, c) __builtin_amdgcn_mfma_f32_32x32x16_f16((a), (b), (c), 0, 0, 0)

__device__ __forceinline__ void gl2lds16(const void* g, void* l) {
    __builtin_amdgcn_global_load_lds(
        (const __attribute__((address_space(1))) unsigned int*)g,
        (__attribute__((address_space(3))) unsigned int*)l,
        16, 0, 0);
}

// ---------------------------------------------------------------------------
// GEMM: C[M,N] = A[M,K] @ W[N,K]^T + bias[N]   (fp32, unchanged from R1)
// ---------------------------------------------------------------------------
__global__ __launch_bounds__(256, 2)
void sgemm_bt_bias(const float* __restrict__ A, const float* __restrict__ W,
                   const float* __restrict__ bias, float* __restrict__ C,
                   int M, int N, int K)
{
    __shared__ float As[16][128 + 4];
    __shared__ float Bs[16][128 + 4];

    const int tid = threadIdx.x;
    const int ty  = tid >> 4;
    const int tx  = tid & 15;
    const int bm  = blockIdx.x * 128;
    const int bn  = blockIdx.y * 128;

    float acc[8][8];
#pragma unroll
    for (int i = 0; i < 8; ++i)
#pragma unroll
        for (int j = 0; j < 8; ++j) acc[i][j] = 0.f;

    for (int k0 = 0; k0 < K; k0 += 16) {
#pragma unroll
        for (int i = 0; i < 2; ++i) {
            const int l  = tid + i * 256;
            const int r  = l >> 2;
            const int k4 = (l & 3) << 2;
            const float4 va = *reinterpret_cast<const float4*>(
                A + (size_t)(bm + r) * K + k0 + k4);
            As[k4 + 0][r] = va.x; As[k4 + 1][r] = va.y;
            As[k4 + 2][r] = va.z; As[k4 + 3][r] = va.w;
            const float4 vb = *reinterpret_cast<const float4*>(
                W + (size_t)(bn + r) * K + k0 + k4);
            Bs[k4 + 0][r] = vb.x; Bs[k4 + 1][r] = vb.y;
            Bs[k4 + 2][r] = vb.z; Bs[k4 + 3][r] = vb.w;
        }
        __syncthreads();
#pragma unroll
        for (int kk = 0; kk < 16; ++kk) {
            float a[8], b[8];
            *reinterpret_cast<float4*>(&a[0]) =
                *reinterpret_cast<const float4*>(&As[kk][ty * 4]);
            *reinterpret_cast<float4*>(&a[4]) =
                *reinterpret_cast<const float4*>(&As[kk][64 + ty * 4]);
            *reinterpret_cast<float4*>(&b[0]) =
                *reinterpret_cast<const float4*>(&Bs[kk][tx * 4]);
            *reinterpret_cast<float4*>(&b[4]) =
                *reinterpret_cast<const float4*>(&Bs[kk][64 + tx * 4]);
#pragma unroll
            for (int i = 0; i < 8; ++i)
#pragma unroll
                for (int j = 0; j < 8; ++j)
                    acc[i][j] = fmaf(a[i], b[j], acc[i][j]);
        }
        __syncthreads();
    }

    float bj[8];
#pragma unroll
    for (int j = 0; j < 8; ++j) {
        const int col = bn + ((j < 4) ? (tx * 4 + j) : (64 + tx * 4 + (j - 4)));
        bj[j] = bias[col];
    }
#pragma unroll
    for (int i = 0; i < 8; ++i) {
        const int row = bm + ((i < 4) ? (ty * 4 + i) : (64 + ty * 4 + (i - 4)));
        float4 o0, o1;
        o0.x = acc[i][0] + bj[0]; o0.y = acc[i][1] + bj[1];
        o0.z = acc[i][2] + bj[2]; o0.w = acc[i][3] + bj[3];
        o1.x = acc[i][4] + bj[4]; o1.y = acc[i][5] + bj[5];
        o1.z = acc[i][6] + bj[6]; o1.w = acc[i][7] + bj[7];
        *reinterpret_cast<float4*>(C + (size_t)row * N + bn + tx * 4)      = o0;
        *reinterpret_cast<float4*>(C + (size_t)row * N + bn + 64 + tx * 4) = o1;
    }
}

// ---------------------------------------------------------------------------
// Prep: qkv fp32 -> per-head fp16 hi/lo K and V^T tiles, XOR-swizzle baked in.
// Layout per (bh, kt): 64x64 halfs. K: elem (key,d) at key*64 + (d ^ ((key&7)<<3)).
// Vt: elem (d,key) at d*64 + (key ^ ((d&7)<<3)).  One block per (kt, bh).
// ---------------------------------------------------------------------------
__global__ __launch_bounds__(256, 2)
void prep_kv(const float* __restrict__ qkv,
             _Float16* __restrict__ Kh, _Float16* __restrict__ Kl,
             _Float16* __restrict__ Vh, _Float16* __restrict__ Vl)
{
    __shared__ float Vf[64][65];
    const int kt = blockIdx.x;
    const int bh = blockIdx.y;
    const int b  = bh >> 4, h = bh & 15;
    const int t  = threadIdx.x;
    const int key = t >> 2;
    const int dg  = (t & 3) * 16;

    const size_t rowbase = ((size_t)b * S_ + kt * 64 + key) * (3 * H_);
    const size_t tb = ((size_t)bh * 32 + kt) * 4096;

    // K: convert + swizzled store
    const float* krow = qkv + rowbase + H_ + h * HD_;
#pragma unroll
    for (int g = 0; g < 4; ++g) {
        const int d0 = dg + g * 4;
        const float4 v = *reinterpret_cast<const float4*>(krow + d0);
        float vf[4] = {v.x, v.y, v.z, v.w};
        half4v hi, lo;
#pragma unroll
        for (int e = 0; e < 4; ++e) {
            _Float16 hv = (_Float16)vf[e];
            hi[e] = hv;
            lo[e] = (_Float16)(vf[e] - (float)hv);
        }
        const int idx = key * 64 + (d0 ^ ((key & 7) << 3));
        *reinterpret_cast<half4v*>(Kh + tb + idx) = hi;
        *reinterpret_cast<half4v*>(Kl + tb + idx) = lo;
    }

    // V: coalesced read -> LDS -> transposed swizzled store
    const float* vrow = qkv + rowbase + 2 * H_ + h * HD_;
#pragma unroll
    for (int g = 0; g < 4; ++g) {
        const int d0 = dg + g * 4;
        const float4 v = *reinterpret_cast<const float4*>(vrow + d0);
        Vf[key][d0 + 0] = v.x; Vf[key][d0 + 1] = v.y;
        Vf[key][d0 + 2] = v.z; Vf[key][d0 + 3] = v.w;
    }
    __syncthreads();
    const int d  = t >> 2;
    const int kg = (t & 3) * 16;
#pragma unroll
    for (int m = 0; m < 8; ++m) {
        const int k2 = kg + 2 * m;
        const float a = Vf[k2][d], c = Vf[k2 + 1][d];
        union { _Float16 h[2]; unsigned u; } hw, lw;
        hw.h[0] = (_Float16)a; hw.h[1] = (_Float16)c;
        lw.h[0] = (_Float16)(a - (float)hw.h[0]);
        lw.h[1] = (_Float16)(c - (float)hw.h[1]);
        const int idx = d * 64 + (k2 ^ ((d & 7) << 3));
        *reinterpret_cast<unsigned*>(Vh + tb + idx) = hw.u;
        *reinterpret_cast<unsigned*>(Vl + tb + idx) = lw.u;
    }
}

// ---------------------------------------------------------------------------
// Flash attention, split-fp16 MFMA 32x32x16, swapped-QK (lane owns one q col).
// 4 waves x 32 q-rows = 128 q/block; K-tile 64. grid 512 (XCD-chunked).
// ---------------------------------------------------------------------------
__global__ __launch_bounds__(256, 2)
void attn_mfma(const float* __restrict__ qkv, const float* __restrict__ mask,
               const _Float16* __restrict__ Kh, const _Float16* __restrict__ Kl,
               const _Float16* __restrict__ Vh, const _Float16* __restrict__ Vl,
               float* __restrict__ av)
{
    __shared__ __align__(16) unsigned char smem[40960];
    _Float16* sKh = (_Float16*)(smem);
    _Float16* sKl = (_Float16*)(smem + 8192);
    _Float16* sVh = (_Float16*)(smem + 16384);
    _Float16* sVl = (_Float16*)(smem + 24576);
    float*    sM  = (float*)(smem + 32768);
    float*    sO  = (float*)(smem);            // epilogue alias [128][68]

    const int tid  = threadIdx.x;
    const int w    = tid >> 6;
    const int lane = tid & 63;
    const int lq   = lane & 31;
    const int hh   = lane >> 5;

    // XCD-chunked swizzle: 512 blocks -> each XCD gets 4 consecutive bh
    const int bid = blockIdx.x;
    const int wg  = (bid & 7) * 64 + (bid >> 3);
    const int bh  = wg >> 4;
    const int qb  = wg & 15;
    const int b   = bh >> 4, h = bh & 15;

    // mask -> LDS (2048 f32)
    {
        const float4* mg = reinterpret_cast<const float4*>(mask);
        float4* ms = reinterpret_cast<float4*>(sM);
        ms[tid]       = mg[tid];
        ms[tid + 256] = mg[tid + 256];
    }

    // Q fragments (B-operand of swapped QK), fp16 split, in registers
    const int qrow = b * S_ + qb * 128 + w * 32 + lq;
    half8 qh[4], ql[4];
#pragma unroll
    for (int ks = 0; ks < 4; ++ks) {
        const float* qp = qkv + (size_t)qrow * (3 * H_) + h * HD_ + ks * 16 + hh * 8;
        const float4 a = *reinterpret_cast<const float4*>(qp);
        const float4 c = *reinterpret_cast<const float4*>(qp + 4);
        float qf[8] = {a.x, a.y, a.z, a.w, c.x, c.y, c.z, c.w};
#pragma unroll
        for (int e = 0; e < 8; ++e) {
            _Float16 hv = (_Float16)qf[e];
            qh[ks][e] = hv;
            ql[ks][e] = (_Float16)(qf[e] - (float)hv);
        }
    }

    f32x16 o0 = {0,0,0,0,0,0,0,0,0,0,0,0,0,0,0,0};
    f32x16 o1 = {0,0,0,0,0,0,0,0,0,0,0,0,0,0,0,0};
    float m_run = -INFINITY, l_run = 0.f;

    const size_t bhbase = (size_t)bh * 32 * 4096;

    for (int kt = 0; kt < 32; ++kt) {
        __syncthreads();
        // stage 4 x 8KB tiles via global_load_lds (linear; swizzle pre-baked)
        {
            const size_t tb = bhbase + (size_t)kt * 4096;
            const int c0 = w * 2;
#pragma unroll
            for (int i = 0; i < 2; ++i) {
                const int off  = (c0 + i) * 512 + lane * 8;   // halfs
                const int loff = (c0 + i) * 512;
                gl2lds16((const void*)(Kh + tb + off), (void*)(sKh + loff));
                gl2lds16((const void*)(Kl + tb + off), (void*)(sKl + loff));
                gl2lds16((const void*)(Vh + tb + off), (void*)(sVh + loff));
                gl2lds16((const void*)(Vl + tb + off), (void*)(sVl + loff));
            }
        }
        __syncthreads();

        // ---- S^T = K Q^T (split: 3 mfma/term) ----
        f32x16 st[2];
#pragma unroll
        for (int ktt = 0; ktt < 2; ++ktt) {
            f32x16 acc = {0,0,0,0,0,0,0,0,0,0,0,0,0,0,0,0};
            const int key = ktt * 32 + lq;
            const int swz = (key & 7) << 3;
#pragma unroll
            for (int ks = 0; ks < 4; ++ks) {
                const int idx = key * 64 + ((ks * 16 + hh * 8) ^ swz);
                const half8 ka = *reinterpret_cast<const half8*>(sKh + idx);
                const half8 kb = *reinterpret_cast<const half8*>(sKl + idx);
                acc = MFMA32(ka, qh[ks], acc);
                acc = MFMA32(ka, ql[ks], acc);
                acc = MFMA32(kb, qh[ks], acc);
            }
            st[ktt] = acc;
        }

        // ---- mask + scale + online softmax (lane owns q col) ----
        float mx = -INFINITY;
#pragma unroll
        for (int ktt = 0; ktt < 2; ++ktt) {
#pragma unroll
            for (int rr = 0; rr < 4; ++rr) {
                const int key0 = kt * 64 + ktt * 32 + rr * 8 + hh * 4;
                const float4 mk = *reinterpret_cast<const float4*>(sM + key0);
                const float mkv[4] = {mk.x, mk.y, mk.z, mk.w};
#pragma unroll
                for (int c = 0; c < 4; ++c) {
                    const int r = rr * 4 + c;
                    const float tv = (st[ktt][r] + mkv[c]) * 0.125f;
                    st[ktt][r] = tv;
                    mx = fmaxf(mx, tv);
                }
            }
        }
        mx = fmaxf(mx, __shfl_xor(mx, 32));
        const float mnew = fmaxf(m_run, mx);
        const float corr = __expf(m_run - mnew);
        m_run = mnew;
        float ps = 0.f;
#pragma unroll
        for (int ktt = 0; ktt < 2; ++ktt)
#pragma unroll
            for (int r = 0; r < 16; ++r) {
                const float p = __expf(st[ktt][r] - mnew);
                st[ktt][r] = p;
                ps += p;
            }
        ps += __shfl_xor(ps, 32);
        l_run = l_run * corr + ps;
#pragma unroll
        for (int r = 0; r < 16; ++r) { o0[r] *= corr; o1[r] *= corr; }

        // ---- pack P (fp16 hi/lo) into words [ktt][rr][pair] ----
        unsigned wph[2][4][2], wpl[2][4][2];
#pragma unroll
        for (int ktt = 0; ktt < 2; ++ktt)
#pragma unroll
            for (int rr = 0; rr < 4; ++rr)
#pragma unroll
                for (int pp = 0; pp < 2; ++pp) {
                    const float p0 = st[ktt][rr * 4 + pp * 2 + 0];
                    const float p1 = st[ktt][rr * 4 + pp * 2 + 1];
                    union { _Float16 h[2]; unsigned u; } a, c;
                    a.h[0] = (_Float16)p0; a.h[1] = (_Float16)p1;
                    c.h[0] = (_Float16)(p0 - (float)a.h[0]);
                    c.h[1] = (_Float16)(p1 - (float)a.h[1]);
                    wph[ktt][rr][pp] = a.u;
                    wpl[ktt][rr][pp] = c.u;
                }

        // ---- assemble P B-frags via shfl_xor(32), then O^T += V^T P^T ----
#pragma unroll
        for (int ks = 0; ks < 4; ++ks) {
            const int i1 = ks >> 1;
            const int rA = (ks & 1) * 2;
            union { unsigned u[4]; half8 v; } ph, pl;
            {
                const unsigned oA0 = wph[i1][rA + 0][0], oB0 = wph[i1][rA + 0][1];
                const unsigned oA1 = wph[i1][rA + 1][0], oB1 = wph[i1][rA + 1][1];
                const unsigned sA1 = (unsigned)__shfl_xor((int)oA1, 32);
                const unsigned sB1 = (unsigned)__shfl_xor((int)oB1, 32);
                const unsigned sA0 = (unsigned)__shfl_xor((int)oA0, 32);
                const unsigned sB0 = (unsigned)__shfl_xor((int)oB0, 32);
                ph.u[0] = hh ? sA1 : oA0;
                ph.u[1] = hh ? sB1 : oB0;
                ph.u[2] = hh ? oA1 : sA0;
                ph.u[3] = hh ? oB1 : sB0;
            }
            {
                const unsigned oA0 = wpl[i1][rA + 0][0], oB0 = wpl[i1][rA + 0][1];
                const unsigned oA1 = wpl[i1][rA + 1][0], oB1 = wpl[i1][rA + 1][1];
                const unsigned sA1 = (unsigned)__shfl_xor((int)oA1, 32);
                const unsigned sB1 = (unsigned)__shfl_xor((int)oB1, 32);
                const unsigned sA0 = (unsigned)__shfl_xor((int)oA0, 32);
                const unsigned sB0 = (unsigned)__shfl_xor((int)oB0, 32);
                pl.u[0] = hh ? sA1 : oA0;
                pl.u[1] = hh ? sB1 : oB0;
                pl.u[2] = hh ? oA1 : sA0;
                pl.u[3] = hh ? oB1 : sB0;
            }
#pragma unroll
            for (int dt = 0; dt < 2; ++dt) {
                const int d = dt * 32 + lq;
                const int idx = d * 64 + ((ks * 16 + hh * 8) ^ ((d & 7) << 3));
                const half8 va = *reinterpret_cast<const half8*>(sVh + idx);
                const half8 vb = *reinterpret_cast<const half8*>(sVl + idx);
                if (dt == 0) {
                    o0 = MFMA32(va, ph.v, o0);
                    o0 = MFMA32(va, pl.v, o0);
                    o0 = MFMA32(vb, ph.v, o0);
                } else {
                    o1 = MFMA32(va, ph.v, o1);
                    o1 = MFMA32(va, pl.v, o1);
                    o1 = MFMA32(vb, ph.v, o1);
                }
            }
        }
    }

    // ---- epilogue: normalize, LDS transpose, coalesced av write ----
    __syncthreads();
    const float inv = 1.f / l_run;
#pragma unroll
    for (int dt = 0; dt < 2; ++dt)
#pragma unroll
        for (int r = 0; r < 16; ++r) {
            const int d = dt * 32 + (r & 3) + 8 * (r >> 2) + 4 * hh;
            const float val = (dt ? o1[r] : o0[r]) * inv;
            sO[(w * 32 + lq) * 68 + d] = val;
        }
    __syncthreads();
    {
        const int c4 = (tid & 15) * 4;
#pragma unroll
        for (int pass = 0; pass < 8; ++pass) {
            const int q = pass * 16 + (tid >> 4);
            const float4 v = *reinterpret_cast<const float4*>(&sO[q * 68 + c4]);
            *reinterpret_cast<float4*>(
                av + ((size_t)b * S_ + qb * 128 + q) * H_ + h * HD_ + c4) = v;
        }
    }
}

// ---------------------------------------------------------------------------
extern "C" void kernel_launch(void* const* d_in, const int* in_sizes, int n_in,
                              void* d_out, int out_size, void* d_ws, size_t ws_size,
                              hipStream_t stream)
{
    const float* x     = (const float*)d_in[0];
    const float* mask  = (const float*)d_in[1];
    const float* w_qkv = (const float*)d_in[2];
    const float* b_qkv = (const float*)d_in[3];
    const float* w_o   = (const float*)d_in[4];
    const float* b_o   = (const float*)d_in[5];
    float* out = (float*)d_out;

    float* qkv = (float*)d_ws;                           // 48 MB
    float* av  = qkv + (size_t)B_ * S_ * 3 * H_;         // 16 MB
    _Float16* hbase = (_Float16*)((char*)d_ws + (size_t)64 * 1024 * 1024);
    const size_t harr = (size_t)32 * 32 * 4096;          // 4 Mi halfs = 8 MB
    _Float16* Kh = hbase;
    _Float16* Kl = hbase + harr;
    _Float16* Vh = hbase + 2 * harr;
    _Float16* Vl = hbase + 3 * harr;

    const dim3 blk(256);
    sgemm_bt_bias<<<dim3(32, 24), blk, 0, stream>>>(x, w_qkv, b_qkv, qkv,
                                                    B_ * S_, 3 * H_, H_);
    prep_kv<<<dim3(32, 32), blk, 0, stream>>>(qkv, Kh, Kl, Vh, Vl);
    attn_mfma<<<dim3(512), blk, 0, stream>>>(qkv, mask, Kh, Kl, Vh, Vl, av);
    sgemm_bt_bias<<<dim3(32, 8), blk, 0, stream>>>(av, w_o, b_o, out,
                                                   B_ * S_, H_, H_);
}

// Round 3
// 376.984 us; speedup vs baseline: 2.6859x; 1.6631x over previous
//
#include <hip/hip_runtime.h>
#include <cmath>

#define B_  2
#define S_  2048
#define H_  1024
#define NH_ 16
#define HD_ 64

typedef _Float16 half8  __attribute__((ext_vector_type(8)));
typedef _Float16 half4v __attribute__((ext_vector_type(4)));
typedef float    f32x16 __attribute__((ext_vector_type(16)));

#define MFMA32(a, b, c) __builtin_amdgcn_mfma_f32_32x32x16_f16((a), (b), (c), 0, 0, 0)

__device__ __forceinline__ void gl2lds16(const void* g, void* l) {
    __builtin_amdgcn_global_load_lds(
        (const __attribute__((address_space(1))) unsigned int*)g,
        (__attribute__((address_space(3))) unsigned int*)l,
        16, 0, 0);
}

// ---------------------------------------------------------------------------
// conv_hilo: src fp32 [R][K] -> hi/lo fp16 in tiled-swizzled layout.
// Tile (rt, kt) of 128x64 at ((rt*(K/64)+kt)*8192); elem (r,g*8+e) at
// r*64 + ((g ^ (r&7))*8 + e).  One block per tile.
// ---------------------------------------------------------------------------
__global__ __launch_bounds__(256, 4)
void conv_hilo(const float* __restrict__ src, _Float16* __restrict__ dh,
               _Float16* __restrict__ dl, int K)
{
    const int bid = blockIdx.x;
    const int nkt = K >> 6;
    const int rt  = bid / nkt;
    const int kt  = bid % nkt;
    const int tid = threadIdx.x;
    const size_t tb = (size_t)bid * 8192;
#pragma unroll
    for (int p = 0; p < 4; ++p) {
        const int idx = p * 256 + tid;   // 0..1023
        const int r   = idx >> 3;        // 0..127
        const int g   = idx & 7;         // 0..7
        const float* s = src + (size_t)(rt * 128 + r) * K + kt * 64 + g * 8;
        const float4 v0 = *reinterpret_cast<const float4*>(s);
        const float4 v1 = *reinterpret_cast<const float4*>(s + 4);
        const float f[8] = {v0.x, v0.y, v0.z, v0.w, v1.x, v1.y, v1.z, v1.w};
        half8 hi, lo;
#pragma unroll
        for (int e = 0; e < 8; ++e) {
            const _Float16 hv = (_Float16)f[e];
            hi[e] = hv;
            lo[e] = (_Float16)(f[e] - (float)hv);
        }
        const int dst = r * 64 + ((g ^ (r & 7)) << 3);
        *reinterpret_cast<half8*>(dh + tb + dst) = hi;
        *reinterpret_cast<half8*>(dl + tb + dst) = lo;
    }
}

// ---------------------------------------------------------------------------
// Split-fp16 MFMA GEMM: C[M,N] = A[M,K] @ W[N,K]^T + bias[N], fp32 out.
// A,W given as hi/lo fp16 tiled-swizzled (conv_hilo layout). 128x128 tile,
// BK=64, 4 waves as 2x2 of 64x64 sub-tiles, mfma 32x32x16, 3 terms/step.
// Grid flattened 1D (nbm*nbn, %8==0), XCD-chunked swizzle.
// ---------------------------------------------------------------------------
__global__ __launch_bounds__(256, 2)
void hgemm_split(const _Float16* __restrict__ Ah, const _Float16* __restrict__ Al,
                 const _Float16* __restrict__ Wh, const _Float16* __restrict__ Wl,
                 const float* __restrict__ bias, float* __restrict__ C,
                 int nbm, int nbn, int nkt, int N)
{
    __shared__ __align__(16) _Float16 sAh[8192];
    __shared__ __align__(16) _Float16 sAl[8192];
    __shared__ __align__(16) _Float16 sWh[8192];
    __shared__ __align__(16) _Float16 sWl[8192];

    const int tid  = threadIdx.x;
    const int w    = tid >> 6;
    const int lane = tid & 63;
    const int lr   = lane & 31;
    const int hh   = lane >> 5;
    const int wm   = w >> 1, wn = w & 1;

    const int nwg = nbm * nbn;
    const int cpx = nwg >> 3;
    const int bid = blockIdx.x;
    const int wg  = (bid & 7) * cpx + (bid >> 3);
    const int mt  = wg / nbn, nt = wg % nbn;

    const size_t aBase = (size_t)mt * nkt * 8192;
    const size_t wBase = (size_t)nt * nkt * 8192;

    f32x16 acc[2][2];
#pragma unroll
    for (int mi = 0; mi < 2; ++mi)
#pragma unroll
        for (int ni = 0; ni < 2; ++ni)
#pragma unroll
            for (int r = 0; r < 16; ++r) acc[mi][ni][r] = 0.f;

    for (int kt = 0; kt < nkt; ++kt) {
        __syncthreads();
        {
            const size_t at = aBase + (size_t)kt * 8192;
            const size_t wt = wBase + (size_t)kt * 8192;
#pragma unroll
            for (int c = 0; c < 4; ++c) {
                const int loff = (w * 4 + c) * 512;          // halfs
                const int goff = loff + lane * 8;
                gl2lds16((const void*)(Ah + at + goff), (void*)(sAh + loff));
                gl2lds16((const void*)(Al + at + goff), (void*)(sAl + loff));
                gl2lds16((const void*)(Wh + wt + goff), (void*)(sWh + loff));
                gl2lds16((const void*)(Wl + wt + goff), (void*)(sWl + loff));
            }
        }
        __syncthreads();

#pragma unroll
        for (int ks = 0; ks < 4; ++ks) {
            const int g = ks * 2 + hh;
            half8 aH[2], aL[2], bH[2], bL[2];
#pragma unroll
            for (int mi = 0; mi < 2; ++mi) {
                const int r   = wm * 64 + mi * 32 + lr;
                const int idx = r * 64 + ((g ^ (r & 7)) << 3);
                aH[mi] = *reinterpret_cast<const half8*>(sAh + idx);
                aL[mi] = *reinterpret_cast<const half8*>(sAl + idx);
            }
#pragma unroll
            for (int ni = 0; ni < 2; ++ni) {
                const int c   = wn * 64 + ni * 32 + lr;
                const int idx = c * 64 + ((g ^ (c & 7)) << 3);
                bH[ni] = *reinterpret_cast<const half8*>(sWh + idx);
                bL[ni] = *reinterpret_cast<const half8*>(sWl + idx);
            }
#pragma unroll
            for (int mi = 0; mi < 2; ++mi)
#pragma unroll
                for (int ni = 0; ni < 2; ++ni) {
                    acc[mi][ni] = MFMA32(aH[mi], bH[ni], acc[mi][ni]);
                    acc[mi][ni] = MFMA32(aH[mi], bL[ni], acc[mi][ni]);
                    acc[mi][ni] = MFMA32(aL[mi], bH[ni], acc[mi][ni]);
                }
        }
    }

    // epilogue: C[m][n] = acc + bias[n]
    const int n0 = nt * 128 + wn * 64 + lr;
    float bv[2];
#pragma unroll
    for (int ni = 0; ni < 2; ++ni) bv[ni] = bias[n0 + ni * 32];
#pragma unroll
    for (int mi = 0; mi < 2; ++mi)
#pragma unroll
        for (int ni = 0; ni < 2; ++ni)
#pragma unroll
            for (int r = 0; r < 16; ++r) {
                const int m = mt * 128 + wm * 64 + mi * 32 +
                              (r & 3) + 8 * (r >> 2) + 4 * hh;
                C[(size_t)m * N + n0 + ni * 32] = acc[mi][ni][r] + bv[ni];
            }
}

// ---------------------------------------------------------------------------
// Prep: qkv fp32 -> per-head fp16 hi/lo K and V^T tiles, swizzle baked in.
// ---------------------------------------------------------------------------
__global__ __launch_bounds__(256, 2)
void prep_kv(const float* __restrict__ qkv,
             _Float16* __restrict__ Kh, _Float16* __restrict__ Kl,
             _Float16* __restrict__ Vh, _Float16* __restrict__ Vl)
{
    __shared__ float Vf[64][65];
    const int kt = blockIdx.x;
    const int bh = blockIdx.y;
    const int b  = bh >> 4, h = bh & 15;
    const int t  = threadIdx.x;
    const int key = t >> 2;
    const int dg  = (t & 3) * 16;

    const size_t rowbase = ((size_t)b * S_ + kt * 64 + key) * (3 * H_);
    const size_t tb = ((size_t)bh * 32 + kt) * 4096;

    const float* krow = qkv + rowbase + H_ + h * HD_;
#pragma unroll
    for (int g = 0; g < 4; ++g) {
        const int d0 = dg + g * 4;
        const float4 v = *reinterpret_cast<const float4*>(krow + d0);
        float vf[4] = {v.x, v.y, v.z, v.w};
        half4v hi, lo;
#pragma unroll
        for (int e = 0; e < 4; ++e) {
            _Float16 hv = (_Float16)vf[e];
            hi[e] = hv;
            lo[e] = (_Float16)(vf[e] - (float)hv);
        }
        const int idx = key * 64 + (d0 ^ ((key & 7) << 3));
        *reinterpret_cast<half4v*>(Kh + tb + idx) = hi;
        *reinterpret_cast<half4v*>(Kl + tb + idx) = lo;
    }

    const float* vrow = qkv + rowbase + 2 * H_ + h * HD_;
#pragma unroll
    for (int g = 0; g < 4; ++g) {
        const int d0 = dg + g * 4;
        const float4 v = *reinterpret_cast<const float4*>(vrow + d0);
        Vf[key][d0 + 0] = v.x; Vf[key][d0 + 1] = v.y;
        Vf[key][d0 + 2] = v.z; Vf[key][d0 + 3] = v.w;
    }
    __syncthreads();
    const int d  = t >> 2;
    const int kg = (t & 3) * 16;
#pragma unroll
    for (int m = 0; m < 8; ++m) {
        const int k2 = kg + 2 * m;
        const float a = Vf[k2][d], c = Vf[k2 + 1][d];
        union { _Float16 h[2]; unsigned u; } hw, lw;
        hw.h[0] = (_Float16)a; hw.h[1] = (_Float16)c;
        lw.h[0] = (_Float16)(a - (float)hw.h[0]);
        lw.h[1] = (_Float16)(c - (float)hw.h[1]);
        const int idx = d * 64 + (k2 ^ ((d & 7) << 3));
        *reinterpret_cast<unsigned*>(Vh + tb + idx) = hw.u;
        *reinterpret_cast<unsigned*>(Vl + tb + idx) = lw.u;
    }
}

// ---------------------------------------------------------------------------
// Flash attention, split-fp16 MFMA 32x32x16, swapped-QK. Writes av directly
// as hi/lo fp16 tiles in the hgemm operand layout (tile (b*16+qb)*16 + h).
// ---------------------------------------------------------------------------
__global__ __launch_bounds__(256, 2)
void attn_mfma(const float* __restrict__ qkv, const float* __restrict__ mask,
               const _Float16* __restrict__ Kh, const _Float16* __restrict__ Kl,
               const _Float16* __restrict__ Vh, const _Float16* __restrict__ Vl,
               _Float16* __restrict__ Avh, _Float16* __restrict__ Avl)
{
    __shared__ __align__(16) unsigned char smem[40960];
    _Float16* sKh = (_Float16*)(smem);
    _Float16* sKl = (_Float16*)(smem + 8192);
    _Float16* sVh = (_Float16*)(smem + 16384);
    _Float16* sVl = (_Float16*)(smem + 24576);
    float*    sM  = (float*)(smem + 32768);
    float*    sO  = (float*)(smem);            // epilogue alias [128][68]

    const int tid  = threadIdx.x;
    const int w    = tid >> 6;
    const int lane = tid & 63;
    const int lq   = lane & 31;
    const int hh   = lane >> 5;

    const int bid = blockIdx.x;
    const int wg  = (bid & 7) * 64 + (bid >> 3);
    const int bh  = wg >> 4;
    const int qb  = wg & 15;
    const int b   = bh >> 4, h = bh & 15;

    {
        const float4* mg = reinterpret_cast<const float4*>(mask);
        float4* ms = reinterpret_cast<float4*>(sM);
        ms[tid]       = mg[tid];
        ms[tid + 256] = mg[tid + 256];
    }

    const int qrow = b * S_ + qb * 128 + w * 32 + lq;
    half8 qh[4], ql[4];
#pragma unroll
    for (int ks = 0; ks < 4; ++ks) {
        const float* qp = qkv + (size_t)qrow * (3 * H_) + h * HD_ + ks * 16 + hh * 8;
        const float4 a = *reinterpret_cast<const float4*>(qp);
        const float4 c = *reinterpret_cast<const float4*>(qp + 4);
        float qf[8] = {a.x, a.y, a.z, a.w, c.x, c.y, c.z, c.w};
#pragma unroll
        for (int e = 0; e < 8; ++e) {
            _Float16 hv = (_Float16)qf[e];
            qh[ks][e] = hv;
            ql[ks][e] = (_Float16)(qf[e] - (float)hv);
        }
    }

    f32x16 o0 = {0,0,0,0,0,0,0,0,0,0,0,0,0,0,0,0};
    f32x16 o1 = {0,0,0,0,0,0,0,0,0,0,0,0,0,0,0,0};
    float m_run = -INFINITY, l_run = 0.f;

    const size_t bhbase = (size_t)bh * 32 * 4096;

    for (int kt = 0; kt < 32; ++kt) {
        __syncthreads();
        {
            const size_t tb = bhbase + (size_t)kt * 4096;
            const int c0 = w * 2;
#pragma unroll
            for (int i = 0; i < 2; ++i) {
                const int off  = (c0 + i) * 512 + lane * 8;
                const int loff = (c0 + i) * 512;
                gl2lds16((const void*)(Kh + tb + off), (void*)(sKh + loff));
                gl2lds16((const void*)(Kl + tb + off), (void*)(sKl + loff));
                gl2lds16((const void*)(Vh + tb + off), (void*)(sVh + loff));
                gl2lds16((const void*)(Vl + tb + off), (void*)(sVl + loff));
            }
        }
        __syncthreads();

        f32x16 st[2];
#pragma unroll
        for (int ktt = 0; ktt < 2; ++ktt) {
            f32x16 acc = {0,0,0,0,0,0,0,0,0,0,0,0,0,0,0,0};
            const int key = ktt * 32 + lq;
            const int swz = (key & 7) << 3;
#pragma unroll
            for (int ks = 0; ks < 4; ++ks) {
                const int idx = key * 64 + ((ks * 16 + hh * 8) ^ swz);
                const half8 ka = *reinterpret_cast<const half8*>(sKh + idx);
                const half8 kb = *reinterpret_cast<const half8*>(sKl + idx);
                acc = MFMA32(ka, qh[ks], acc);
                acc = MFMA32(ka, ql[ks], acc);
                acc = MFMA32(kb, qh[ks], acc);
            }
            st[ktt] = acc;
        }

        float mx = -INFINITY;
#pragma unroll
        for (int ktt = 0; ktt < 2; ++ktt) {
#pragma unroll
            for (int rr = 0; rr < 4; ++rr) {
                const int key0 = kt * 64 + ktt * 32 + rr * 8 + hh * 4;
                const float4 mk = *reinterpret_cast<const float4*>(sM + key0);
                const float mkv[4] = {mk.x, mk.y, mk.z, mk.w};
#pragma unroll
                for (int c = 0; c < 4; ++c) {
                    const int r = rr * 4 + c;
                    const float tv = (st[ktt][r] + mkv[c]) * 0.125f;
                    st[ktt][r] = tv;
                    mx = fmaxf(mx, tv);
                }
            }
        }
        mx = fmaxf(mx, __shfl_xor(mx, 32));
        const float mnew = fmaxf(m_run, mx);
        const float corr = __expf(m_run - mnew);
        m_run = mnew;
        float ps = 0.f;
#pragma unroll
        for (int ktt = 0; ktt < 2; ++ktt)
#pragma unroll
            for (int r = 0; r < 16; ++r) {
                const float p = __expf(st[ktt][r] - mnew);
                st[ktt][r] = p;
                ps += p;
            }
        ps += __shfl_xor(ps, 32);
        l_run = l_run * corr + ps;
#pragma unroll
        for (int r = 0; r < 16; ++r) { o0[r] *= corr; o1[r] *= corr; }

        unsigned wph[2][4][2], wpl[2][4][2];
#pragma unroll
        for (int ktt = 0; ktt < 2; ++ktt)
#pragma unroll
            for (int rr = 0; rr < 4; ++rr)
#pragma unroll
                for (int pp = 0; pp < 2; ++pp) {
                    const float p0 = st[ktt][rr * 4 + pp * 2 + 0];
                    const float p1 = st[ktt][rr * 4 + pp * 2 + 1];
                    union { _Float16 h[2]; unsigned u; } a, c;
                    a.h[0] = (_Float16)p0; a.h[1] = (_Float16)p1;
                    c.h[0] = (_Float16)(p0 - (float)a.h[0]);
                    c.h[1] = (_Float16)(p1 - (float)a.h[1]);
                    wph[ktt][rr][pp] = a.u;
                    wpl[ktt][rr][pp] = c.u;
                }

#pragma unroll
        for (int ks = 0; ks < 4; ++ks) {
            const int i1 = ks >> 1;
            const int rA = (ks & 1) * 2;
            union { unsigned u[4]; half8 v; } ph, pl;
            {
                const unsigned oA0 = wph[i1][rA + 0][0], oB0 = wph[i1][rA + 0][1];
                const unsigned oA1 = wph[i1][rA + 1][0], oB1 = wph[i1][rA + 1][1];
                const unsigned sA1 = (unsigned)__shfl_xor((int)oA1, 32);
                const unsigned sB1 = (unsigned)__shfl_xor((int)oB1, 32);
                const unsigned sA0 = (unsigned)__shfl_xor((int)oA0, 32);
                const unsigned sB0 = (unsigned)__shfl_xor((int)oB0, 32);
                ph.u[0] = hh ? sA1 : oA0;
                ph.u[1] = hh ? sB1 : oB0;
                ph.u[2] = hh ? oA1 : sA0;
                ph.u[3] = hh ? oB1 : sB0;
            }
            {
                const unsigned oA0 = wpl[i1][rA + 0][0], oB0 = wpl[i1][rA + 0][1];
                const unsigned oA1 = wpl[i1][rA + 1][0], oB1 = wpl[i1][rA + 1][1];
                const unsigned sA1 = (unsigned)__shfl_xor((int)oA1, 32);
                const unsigned sB1 = (unsigned)__shfl_xor((int)oB1, 32);
                const unsigned sA0 = (unsigned)__shfl_xor((int)oA0, 32);
                const unsigned sB0 = (unsigned)__shfl_xor((int)oB0, 32);
                pl.u[0] = hh ? sA1 : oA0;
                pl.u[1] = hh ? sB1 : oB0;
                pl.u[2] = hh ? oA1 : sA0;
                pl.u[3] = hh ? oB1 : sB0;
            }
#pragma unroll
            for (int dt = 0; dt < 2; ++dt) {
                const int d = dt * 32 + lq;
                const int idx = d * 64 + ((ks * 16 + hh * 8) ^ ((d & 7) << 3));
                const half8 va = *reinterpret_cast<const half8*>(sVh + idx);
                const half8 vb = *reinterpret_cast<const half8*>(sVl + idx);
                if (dt == 0) {
                    o0 = MFMA32(va, ph.v, o0);
                    o0 = MFMA32(va, pl.v, o0);
                    o0 = MFMA32(vb, ph.v, o0);
                } else {
                    o1 = MFMA32(va, ph.v, o1);
                    o1 = MFMA32(va, pl.v, o1);
                    o1 = MFMA32(vb, ph.v, o1);
                }
            }
        }
    }

    // epilogue: normalize, transpose via LDS, emit hi/lo swizzled Av tile
    __syncthreads();
    const float inv = 1.f / l_run;
#pragma unroll
    for (int dt = 0; dt < 2; ++dt)
#pragma unroll
        for (int r = 0; r < 16; ++r) {
            const int d = dt * 32 + (r & 3) + 8 * (r >> 2) + 4 * hh;
            sO[(w * 32 + lq) * 68 + d] = (dt ? o1[r] : o0[r]) * inv;
        }
    __syncthreads();
    {
        const size_t tb = (((size_t)(b * 16 + qb)) * 16 + h) * 8192;
#pragma unroll
        for (int p = 0; p < 4; ++p) {
            const int idx = p * 256 + tid;
            const int q = idx >> 3, g = idx & 7;
            const float4 v0 = *reinterpret_cast<const float4*>(&sO[q * 68 + g * 8]);
            const float4 v1 = *reinterpret_cast<const float4*>(&sO[q * 68 + g * 8 + 4]);
            const float f[8] = {v0.x, v0.y, v0.z, v0.w, v1.x, v1.y, v1.z, v1.w};
            half8 hi, lo;
#pragma unroll
            for (int e = 0; e < 8; ++e) {
                const _Float16 hv = (_Float16)f[e];
                hi[e] = hv;
                lo[e] = (_Float16)(f[e] - (float)hv);
            }
            const int dst = q * 64 + ((g ^ (q & 7)) << 3);
            *reinterpret_cast<half8*>(Avh + tb + dst) = hi;
            *reinterpret_cast<half8*>(Avl + tb + dst) = lo;
        }
    }
}

// ---------------------------------------------------------------------------
extern "C" void kernel_launch(void* const* d_in, const int* in_sizes, int n_in,
                              void* d_out, int out_size, void* d_ws, size_t ws_size,
                              hipStream_t stream)
{
    const float* x     = (const float*)d_in[0];
    const float* mask  = (const float*)d_in[1];
    const float* w_qkv = (const float*)d_in[2];
    const float* b_qkv = (const float*)d_in[3];
    const float* w_o   = (const float*)d_in[4];
    const float* b_o   = (const float*)d_in[5];
    float* out = (float*)d_out;

    char* p = (char*)d_ws;
    float* qkv = (float*)p;                 p += (size_t)4096 * 3072 * 4;  // 48 MB
    _Float16* Kh  = (_Float16*)p;           p += (size_t)32 * 32 * 4096 * 2;
    _Float16* Kl  = (_Float16*)p;           p += (size_t)32 * 32 * 4096 * 2;
    _Float16* Vh  = (_Float16*)p;           p += (size_t)32 * 32 * 4096 * 2;
    _Float16* Vl  = (_Float16*)p;           p += (size_t)32 * 32 * 4096 * 2;
    _Float16* Xh  = (_Float16*)p;           p += (size_t)4096 * 1024 * 2;
    _Float16* Xl  = (_Float16*)p;           p += (size_t)4096 * 1024 * 2;
    _Float16* Wqh = (_Float16*)p;           p += (size_t)3072 * 1024 * 2;
    _Float16* Wql = (_Float16*)p;           p += (size_t)3072 * 1024 * 2;
    _Float16* Woh = (_Float16*)p;           p += (size_t)1024 * 1024 * 2;
    _Float16* Wol = (_Float16*)p;           p += (size_t)1024 * 1024 * 2;
    _Float16* Avh = (_Float16*)p;           p += (size_t)4096 * 1024 * 2;
    _Float16* Avl = (_Float16*)p;           p += (size_t)4096 * 1024 * 2;

    const dim3 blk(256);
    conv_hilo<<<dim3(32 * 16), blk, 0, stream>>>(x,     Xh,  Xl,  1024);
    conv_hilo<<<dim3(24 * 16), blk, 0, stream>>>(w_qkv, Wqh, Wql, 1024);
    conv_hilo<<<dim3(8 * 16),  blk, 0, stream>>>(w_o,   Woh, Wol, 1024);

    // QKV projection: M=4096 (nbm=32), N=3072 (nbn=24), K=1024 (nkt=16)
    hgemm_split<<<dim3(32 * 24), blk, 0, stream>>>(Xh, Xl, Wqh, Wql,
                                                   b_qkv, qkv, 32, 24, 16, 3072);
    prep_kv<<<dim3(32, 32), blk, 0, stream>>>(qkv, Kh, Kl, Vh, Vl);
    attn_mfma<<<dim3(512), blk, 0, stream>>>(qkv, mask, Kh, Kl, Vh, Vl, Avh, Avl);
    // out projection: M=4096 (nbm=32), N=1024 (nbn=8), K=1024
    hgemm_split<<<dim3(32 * 8), blk, 0, stream>>>(Avh, Avl, Woh, Wol,
                                                  b_o, out, 32, 8, 16, 1024);
}

// Round 6
// 343.080 us; speedup vs baseline: 2.9514x; 1.0988x over previous
//
#include <hip/hip_runtime.h>
#include <cmath>

#define B_  2
#define S_  2048
#define H_  1024
#define NH_ 16
#define HD_ 64

typedef _Float16 half8  __attribute__((ext_vector_type(8)));
typedef __fp16   fp16x2 __attribute__((ext_vector_type(2)));
typedef float    f32x16 __attribute__((ext_vector_type(16)));

#define MFMA32(a, b, c) __builtin_amdgcn_mfma_f32_32x32x16_f16((a), (b), (c), 0, 0, 0)

__device__ __forceinline__ void gl2lds16(const void* g, void* l) {
    __builtin_amdgcn_global_load_lds(
        (const __attribute__((address_space(1))) unsigned int*)g,
        (__attribute__((address_space(3))) unsigned int*)l,
        16, 0, 0);
}

__device__ __forceinline__ unsigned pk16(float a, float b) {
    union { fp16x2 v; unsigned u; } c;
    c.v = __builtin_amdgcn_cvt_pkrtz(a, b);
    return c.u;
}

// ---------------------------------------------------------------------------
// conv_hilo: src fp32 [R][K] -> hi/lo fp16 tiled-swizzled (128x64 tiles).
// elem (r, g*8+e) of tile at r*64 + ((g ^ (r&7))*8 + e).
// ---------------------------------------------------------------------------
__global__ __launch_bounds__(256, 4)
void conv_hilo(const float* __restrict__ src, _Float16* __restrict__ dh,
               _Float16* __restrict__ dl, int K)
{
    const int bid = blockIdx.x;
    const int nkt = K >> 6;
    const int rt  = bid / nkt;
    const int kt  = bid % nkt;
    const int tid = threadIdx.x;
    const size_t tb = (size_t)bid * 8192;
#pragma unroll
    for (int p = 0; p < 4; ++p) {
        const int idx = p * 256 + tid;
        const int r   = idx >> 3;
        const int g   = idx & 7;
        const float* s = src + (size_t)(rt * 128 + r) * K + kt * 64 + g * 8;
        const float4 v0 = *reinterpret_cast<const float4*>(s);
        const float4 v1 = *reinterpret_cast<const float4*>(s + 4);
        const float f[8] = {v0.x, v0.y, v0.z, v0.w, v1.x, v1.y, v1.z, v1.w};
        half8 hi, lo;
#pragma unroll
        for (int e = 0; e < 8; ++e) {
            const _Float16 hv = (_Float16)f[e];
            hi[e] = hv;
            lo[e] = (_Float16)(f[e] - (float)hv);
        }
        const int dst = r * 64 + ((g ^ (r & 7)) << 3);
        *reinterpret_cast<half8*>(dh + tb + dst) = hi;
        *reinterpret_cast<half8*>(dl + tb + dst) = lo;
    }
}

// ---------------------------------------------------------------------------
// Split-fp16 MFMA GEMM, 128x128 tile, BK=64, 4 waves (2x2 of 64x64).
// QKV=0: C[m][n] = acc + bias (fp32).  QKV=1: fused epilogue writing
//   n<1024  -> Q fp32 [4096][1024]
//   n<2048  -> K hi/lo attention tiles (key*64 + (d ^ ((key&7)<<3)))
//   else    -> V^T hi/lo attention tiles (d*64 + (key ^ ((d&7)<<3)))
// ---------------------------------------------------------------------------
template<int QKV>
__global__ __launch_bounds__(256, 2)
void hgemm_split(const _Float16* __restrict__ Ah, const _Float16* __restrict__ Al,
                 const _Float16* __restrict__ Wh, const _Float16* __restrict__ Wl,
                 const float* __restrict__ bias, float* __restrict__ C,
                 float* __restrict__ Qo,
                 _Float16* __restrict__ Kh, _Float16* __restrict__ Kl,
                 _Float16* __restrict__ Vh, _Float16* __restrict__ Vl,
                 int nbm, int nbn, int nkt, int N)
{
    __shared__ __align__(16) unsigned char smem[65536];
    _Float16* sAh = (_Float16*)(smem);
    _Float16* sAl = (_Float16*)(smem + 16384);
    _Float16* sWh = (_Float16*)(smem + 32768);
    _Float16* sWl = (_Float16*)(smem + 49152);

    const int tid  = threadIdx.x;
    const int w    = tid >> 6;
    const int lane = tid & 63;
    const int lr   = lane & 31;
    const int hh   = lane >> 5;
    const int wm   = w >> 1, wn = w & 1;

    const int nwg = nbm * nbn;
    const int cpx = nwg >> 3;
    const int bid = blockIdx.x;
    const int wg  = (bid & 7) * cpx + (bid >> 3);
    const int mt  = wg / nbn, nt = wg % nbn;

    const size_t aBase = (size_t)mt * nkt * 8192;
    const size_t wBase = (size_t)nt * nkt * 8192;

    f32x16 acc[2][2];
#pragma unroll
    for (int mi = 0; mi < 2; ++mi)
#pragma unroll
        for (int ni = 0; ni < 2; ++ni)
#pragma unroll
            for (int r = 0; r < 16; ++r) acc[mi][ni][r] = 0.f;

    for (int kt = 0; kt < nkt; ++kt) {
        __syncthreads();
        {
            const size_t at = aBase + (size_t)kt * 8192;
            const size_t wt = wBase + (size_t)kt * 8192;
#pragma unroll
            for (int c = 0; c < 4; ++c) {
                const int loff = (w * 4 + c) * 512;
                const int goff = loff + lane * 8;
                gl2lds16((const void*)(Ah + at + goff), (void*)(sAh + loff));
                gl2lds16((const void*)(Al + at + goff), (void*)(sAl + loff));
                gl2lds16((const void*)(Wh + wt + goff), (void*)(sWh + loff));
                gl2lds16((const void*)(Wl + wt + goff), (void*)(sWl + loff));
            }
        }
        __syncthreads();

#pragma unroll
        for (int ks = 0; ks < 4; ++ks) {
            const int g = ks * 2 + hh;
            half8 aH[2], aL[2], bH[2], bL[2];
#pragma unroll
            for (int mi = 0; mi < 2; ++mi) {
                const int r   = wm * 64 + mi * 32 + lr;
                const int idx = r * 64 + ((g ^ (r & 7)) << 3);
                aH[mi] = *reinterpret_cast<const half8*>(sAh + idx);
                aL[mi] = *reinterpret_cast<const half8*>(sAl + idx);
            }
#pragma unroll
            for (int ni = 0; ni < 2; ++ni) {
                const int c   = wn * 64 + ni * 32 + lr;
                const int idx = c * 64 + ((g ^ (c & 7)) << 3);
                bH[ni] = *reinterpret_cast<const half8*>(sWh + idx);
                bL[ni] = *reinterpret_cast<const half8*>(sWl + idx);
            }
#pragma unroll
            for (int mi = 0; mi < 2; ++mi)
#pragma unroll
                for (int ni = 0; ni < 2; ++ni) {
                    acc[mi][ni] = MFMA32(aH[mi], bH[ni], acc[mi][ni]);
                    acc[mi][ni] = MFMA32(aH[mi], bL[ni], acc[mi][ni]);
                    acc[mi][ni] = MFMA32(aL[mi], bH[ni], acc[mi][ni]);
                }
        }
    }

    if constexpr (QKV == 0) {
        const int n0 = nt * 128 + wn * 64 + lr;
        float bv[2];
#pragma unroll
        for (int ni = 0; ni < 2; ++ni) bv[ni] = bias[n0 + ni * 32];
#pragma unroll
        for (int mi = 0; mi < 2; ++mi)
#pragma unroll
            for (int ni = 0; ni < 2; ++ni)
#pragma unroll
                for (int r = 0; r < 16; ++r) {
                    const int m = mt * 128 + wm * 64 + mi * 32 +
                                  (r & 3) + 8 * (r >> 2) + 4 * hh;
                    C[(size_t)m * N + n0 + ni * 32] = acc[mi][ni][r] + bv[ni];
                }
    } else {
        // fused QKV epilogue through LDS (two 64-row passes)
        float* sC = (float*)smem;                     // [64][132]
        const int m0  = mt * 128;
        const int b   = m0 >> 11;
        const int kt0 = (m0 & 2047) >> 6;
#pragma unroll
        for (int pass = 0; pass < 2; ++pass) {
            __syncthreads();
            if (wm == pass) {
#pragma unroll
                for (int mi = 0; mi < 2; ++mi)
#pragma unroll
                    for (int ni = 0; ni < 2; ++ni)
#pragma unroll
                        for (int r = 0; r < 16; ++r) {
                            const int ml = mi * 32 + (r & 3) + 8 * (r >> 2) + 4 * hh;
                            sC[ml * 132 + wn * 64 + ni * 32 + lr] = acc[mi][ni][r];
                        }
            }
            __syncthreads();
            const int ktile = kt0 + pass;
            if (nt < 8) {
                // Q region: fp32, coalesced
#pragma unroll
                for (int it = 0; it < 8; ++it) {
                    const int idx = it * 256 + tid;
                    const int row = idx >> 5;
                    const int c4  = (idx & 31) << 2;
                    float4 v = *reinterpret_cast<const float4*>(&sC[row * 132 + c4]);
                    const float4 bv = *reinterpret_cast<const float4*>(bias + nt * 128 + c4);
                    v.x += bv.x; v.y += bv.y; v.z += bv.z; v.w += bv.w;
                    *reinterpret_cast<float4*>(
                        Qo + (size_t)(m0 + pass * 64 + row) * 1024 + nt * 128 + c4) = v;
                }
            } else if (nt < 16) {
                // K region: hi/lo swizzled tiles
#pragma unroll
                for (int it = 0; it < 4; ++it) {
                    const int idx = it * 256 + tid;
                    const int key = idx >> 4;
                    const int g   = idx & 15;
                    const int head = 2 * (nt - 8) + (g >> 3);
                    const int d0   = (g & 7) << 3;
                    float f[8];
#pragma unroll
                    for (int e = 0; e < 8; ++e)
                        f[e] = sC[key * 132 + g * 8 + e] +
                               bias[1024 + (nt - 8) * 128 + g * 8 + e];
                    half8 hi, lo;
#pragma unroll
                    for (int e = 0; e < 8; ++e) {
                        const _Float16 hv = (_Float16)f[e];
                        hi[e] = hv;
                        lo[e] = (_Float16)(f[e] - (float)hv);
                    }
                    const size_t base = ((size_t)(b * 16 + head) * 32 + ktile) * 4096;
                    const size_t dst  = base + key * 64 + (d0 ^ ((key & 7) << 3));
                    *reinterpret_cast<half8*>(Kh + dst) = hi;
                    *reinterpret_cast<half8*>(Kl + dst) = lo;
                }
            } else {
                // V region: transposed hi/lo swizzled tiles
#pragma unroll
                for (int it = 0; it < 4; ++it) {
                    const int idx = it * 256 + tid;
                    const int f   = idx >> 3;        // feature col 0..127
                    const int kg  = idx & 7;         // key-group
                    const int head = 2 * (nt - 16) + (f >> 6);
                    const int d    = f & 63;
                    const float bv = bias[2048 + (nt - 16) * 128 + f];
                    float fe[8];
#pragma unroll
                    for (int e = 0; e < 8; ++e)
                        fe[e] = sC[(kg * 8 + e) * 132 + f] + bv;
                    half8 hi, lo;
#pragma unroll
                    for (int e = 0; e < 8; ++e) {
                        const _Float16 hv = (_Float16)fe[e];
                        hi[e] = hv;
                        lo[e] = (_Float16)(fe[e] - (float)hv);
                    }
                    const size_t base = ((size_t)(b * 16 + head) * 32 + ktile) * 4096;
                    const size_t dst  = base + d * 64 + ((kg * 8) ^ ((d & 7) << 3));
                    *reinterpret_cast<half8*>(Vh + dst) = hi;
                    *reinterpret_cast<half8*>(Vl + dst) = lo;
                }
            }
        }
    }
}

// ---------------------------------------------------------------------------
// Flash attention, split-fp16 MFMA, swapped-QK, double-buffered staging.
// ---------------------------------------------------------------------------
__global__ __launch_bounds__(256, 2)
void attn_mfma(const float* __restrict__ Q, const float* __restrict__ mask,
               const _Float16* __restrict__ Kh, const _Float16* __restrict__ Kl,
               const _Float16* __restrict__ Vh, const _Float16* __restrict__ Vl,
               _Float16* __restrict__ Avh, _Float16* __restrict__ Avl)
{
    __shared__ __align__(16) unsigned char smem[73728];
    // buf0 @0, buf1 @32768; within buf: Kh 0, Kl +4096, Vh +8192, Vl +12288 (halfs)
    float* sM = (float*)(smem + 65536);
    float* sO = (float*)(smem);        // epilogue alias [128][68]

    const int tid  = threadIdx.x;
    const int w    = tid >> 6;
    const int lane = tid & 63;
    const int lq   = lane & 31;
    const int hh   = lane >> 5;

    const int bid = blockIdx.x;
    const int wg  = (bid & 7) * 64 + (bid >> 3);
    const int bh  = wg >> 4;
    const int qb  = wg & 15;
    const int b   = bh >> 4, h = bh & 15;

    // mask * 1/8 -> LDS
    {
        const float4* mg = reinterpret_cast<const float4*>(mask);
        float4* ms = reinterpret_cast<float4*>(sM);
        float4 a = mg[tid], c = mg[tid + 256];
        a.x *= 0.125f; a.y *= 0.125f; a.z *= 0.125f; a.w *= 0.125f;
        c.x *= 0.125f; c.y *= 0.125f; c.z *= 0.125f; c.w *= 0.125f;
        ms[tid] = a; ms[tid + 256] = c;
    }

    // Q fragments scaled by 1/8, fp16 split
    const int qrow = b * S_ + qb * 128 + w * 32 + lq;
    half8 qh[4], ql[4];
#pragma unroll
    for (int ks = 0; ks < 4; ++ks) {
        const float* qp = Q + (size_t)qrow * 1024 + h * HD_ + ks * 16 + hh * 8;
        const float4 a = *reinterpret_cast<const float4*>(qp);
        const float4 c = *reinterpret_cast<const float4*>(qp + 4);
        float qf[8] = {a.x, a.y, a.z, a.w, c.x, c.y, c.z, c.w};
#pragma unroll
        for (int e = 0; e < 8; ++e) {
            const float sv = qf[e] * 0.125f;
            const _Float16 hv = (_Float16)sv;
            qh[ks][e] = hv;
            ql[ks][e] = (_Float16)(sv - (float)hv);
        }
    }

    // loop-invariant swizzled LDS offsets (shared by K and V^T reads)
    const int swz = (lq & 7) << 3;
    int off[2][4];
#pragma unroll
    for (int t2 = 0; t2 < 2; ++t2)
#pragma unroll
        for (int ks = 0; ks < 4; ++ks)
            off[t2][ks] = (t2 * 32 + lq) * 64 + ((ks * 16 + hh * 8) ^ swz);

    f32x16 o0 = {0,0,0,0,0,0,0,0,0,0,0,0,0,0,0,0};
    f32x16 o1 = {0,0,0,0,0,0,0,0,0,0,0,0,0,0,0,0};
    float m_run = -INFINITY, l_run = 0.f;

    const size_t bhbase = (size_t)bh * 32 * 4096;

    // prologue: stage tile 0 into buf0
    {
        const size_t tb = bhbase;
#pragma unroll
        for (int i = 0; i < 2; ++i) {
            const int loff = (w * 2 + i) * 512;
            const int goff = loff + lane * 8;
            _Float16* nb = (_Float16*)smem;
            gl2lds16((const void*)(Kh + tb + goff), (void*)(nb + loff));
            gl2lds16((const void*)(Kl + tb + goff), (void*)(nb + 4096 + loff));
            gl2lds16((const void*)(Vh + tb + goff), (void*)(nb + 8192 + loff));
            gl2lds16((const void*)(Vl + tb + goff), (void*)(nb + 12288 + loff));
        }
    }
    __syncthreads();

    for (int kt = 0; kt < 32; ++kt) {
        _Float16* bb = (_Float16*)(smem + ((kt & 1) << 15));
        // prefetch next tile into the other buffer (issue only; drained by the
        // implicit vmcnt(0) of the barrier at the END of this iteration)
        if (kt < 31) {
            _Float16* nb = (_Float16*)(smem + (((kt + 1) & 1) << 15));
            const size_t tb = bhbase + (size_t)(kt + 1) * 4096;
#pragma unroll
            for (int i = 0; i < 2; ++i) {
                const int loff = (w * 2 + i) * 512;
                const int goff = loff + lane * 8;
                gl2lds16((const void*)(Kh + tb + goff), (void*)(nb + loff));
                gl2lds16((const void*)(Kl + tb + goff), (void*)(nb + 4096 + loff));
                gl2lds16((const void*)(Vh + tb + goff), (void*)(nb + 8192 + loff));
                gl2lds16((const void*)(Vl + tb + goff), (void*)(nb + 12288 + loff));
            }
        }

        // ---- S^T = K Q^T (3-term split) ----
        f32x16 st[2];
#pragma unroll
        for (int ktt = 0; ktt < 2; ++ktt) {
            f32x16 acc = {0,0,0,0,0,0,0,0,0,0,0,0,0,0,0,0};
#pragma unroll
            for (int ks = 0; ks < 4; ++ks) {
                const half8 ka = *reinterpret_cast<const half8*>(bb + off[ktt][ks]);
                const half8 kb = *reinterpret_cast<const half8*>(bb + 4096 + off[ktt][ks]);
                acc = MFMA32(ka, qh[ks], acc);
                acc = MFMA32(ka, ql[ks], acc);
                acc = MFMA32(kb, qh[ks], acc);
            }
            st[ktt] = acc;
        }

        // ---- + mask (pre-scaled), running max ----
        float mx = -INFINITY;
#pragma unroll
        for (int ktt = 0; ktt < 2; ++ktt) {
#pragma unroll
            for (int rr = 0; rr < 4; ++rr) {
                const int key0 = kt * 64 + ktt * 32 + rr * 8 + hh * 4;
                const float4 mk = *reinterpret_cast<const float4*>(sM + key0);
                const float mkv[4] = {mk.x, mk.y, mk.z, mk.w};
#pragma unroll
                for (int c = 0; c < 4; ++c) {
                    const int r = rr * 4 + c;
                    const float tv = st[ktt][r] + mkv[c];
                    st[ktt][r] = tv;
                    mx = fmaxf(mx, tv);
                }
            }
        }
        mx = fmaxf(mx, __shfl_xor(mx, 32));

        // ---- defer-max online softmax (T13, THR=8) ----
        if (!__all(mx - m_run <= 8.0f)) {
            const float mnew = fmaxf(m_run, mx);
            const float corr = __expf(m_run - mnew);
            m_run = mnew;
            l_run *= corr;
#pragma unroll
            for (int r = 0; r < 16; ++r) { o0[r] *= corr; o1[r] *= corr; }
        }
        float ps = 0.f;
#pragma unroll
        for (int ktt = 0; ktt < 2; ++ktt)
#pragma unroll
            for (int r = 0; r < 16; ++r) {
                const float p = __expf(st[ktt][r] - m_run);
                st[ktt][r] = p;
                ps += p;
            }
        ps += __shfl_xor(ps, 32);
        l_run += ps;

        // ---- pack P hi/lo via pkrtz ----
        unsigned wph[2][4][2], wpl[2][4][2];
#pragma unroll
        for (int ktt = 0; ktt < 2; ++ktt)
#pragma unroll
            for (int rr = 0; rr < 4; ++rr)
#pragma unroll
                for (int pp = 0; pp < 2; ++pp) {
                    const float p0 = st[ktt][rr * 4 + pp * 2 + 0];
                    const float p1 = st[ktt][rr * 4 + pp * 2 + 1];
                    union { fp16x2 v; unsigned u; } hw;
                    hw.v = __builtin_amdgcn_cvt_pkrtz(p0, p1);
                    wph[ktt][rr][pp] = hw.u;
                    wpl[ktt][rr][pp] = pk16(p0 - (float)hw.v[0], p1 - (float)hw.v[1]);
                }

        // ---- assemble P B-frags via shfl_xor(32); O^T += V^T P^T ----
#pragma unroll
        for (int ks = 0; ks < 4; ++ks) {
            const int i1 = ks >> 1;
            const int rA = (ks & 1) * 2;
            union { unsigned u[4]; half8 v; } ph, pl;
            {
                const unsigned oA0 = wph[i1][rA + 0][0], oB0 = wph[i1][rA + 0][1];
                const unsigned oA1 = wph[i1][rA + 1][0], oB1 = wph[i1][rA + 1][1];
                const unsigned sA1 = (unsigned)__shfl_xor((int)oA1, 32);
                const unsigned sB1 = (unsigned)__shfl_xor((int)oB1, 32);
                const unsigned sA0 = (unsigned)__shfl_xor((int)oA0, 32);
                const unsigned sB0 = (unsigned)__shfl_xor((int)oB0, 32);
                ph.u[0] = hh ? sA1 : oA0;
                ph.u[1] = hh ? sB1 : oB0;
                ph.u[2] = hh ? oA1 : sA0;
                ph.u[3] = hh ? oB1 : sB0;
            }
            {
                const unsigned oA0 = wpl[i1][rA + 0][0], oB0 = wpl[i1][rA + 0][1];
                const unsigned oA1 = wpl[i1][rA + 1][0], oB1 = wpl[i1][rA + 1][1];
                const unsigned sA1 = (unsigned)__shfl_xor((int)oA1, 32);
                const unsigned sB1 = (unsigned)__shfl_xor((int)oB1, 32);
                const unsigned sA0 = (unsigned)__shfl_xor((int)oA0, 32);
                const unsigned sB0 = (unsigned)__shfl_xor((int)oB0, 32);
                pl.u[0] = hh ? sA1 : oA0;
                pl.u[1] = hh ? sB1 : oB0;
                pl.u[2] = hh ? oA1 : sA0;
                pl.u[3] = hh ? oB1 : sB0;
            }
#pragma unroll
            for (int dt = 0; dt < 2; ++dt) {
                const half8 va = *reinterpret_cast<const half8*>(bb + 8192 + off[dt][ks]);
                const half8 vb = *reinterpret_cast<const half8*>(bb + 12288 + off[dt][ks]);
                if (dt == 0) {
                    o0 = MFMA32(va, ph.v, o0);
                    o0 = MFMA32(va, pl.v, o0);
                    o0 = MFMA32(vb, ph.v, o0);
                } else {
                    o1 = MFMA32(va, ph.v, o1);
                    o1 = MFMA32(va, pl.v, o1);
                    o1 = MFMA32(vb, ph.v, o1);
                }
            }
        }
        __syncthreads();   // joins waves AND drains the kt+1 prefetch
    }

    // ---- epilogue: normalize, LDS transpose, emit hi/lo swizzled Av tile ----
    const float inv = 1.f / l_run;
#pragma unroll
    for (int dt = 0; dt < 2; ++dt)
#pragma unroll
        for (int r = 0; r < 16; ++r) {
            const int d = dt * 32 + (r & 3) + 8 * (r >> 2) + 4 * hh;
            sO[(w * 32 + lq) * 68 + d] = (dt ? o1[r] : o0[r]) * inv;
        }
    __syncthreads();
    {
        const size_t tb = (((size_t)(b * 16 + qb)) * 16 + h) * 8192;
#pragma unroll
        for (int p = 0; p < 4; ++p) {
            const int idx = p * 256 + tid;
            const int q = idx >> 3, g = idx & 7;
            const float4 v0 = *reinterpret_cast<const float4*>(&sO[q * 68 + g * 8]);
            const float4 v1 = *reinterpret_cast<const float4*>(&sO[q * 68 + g * 8 + 4]);
            const float f[8] = {v0.x, v0.y, v0.z, v0.w, v1.x, v1.y, v1.z, v1.w};
            half8 hi, lo;
#pragma unroll
            for (int e = 0; e < 8; ++e) {
                const _Float16 hv = (_Float16)f[e];
                hi[e] = hv;
                lo[e] = (_Float16)(f[e] - (float)hv);
            }
            const int dst = q * 64 + ((g ^ (q & 7)) << 3);
            *reinterpret_cast<half8*>(Avh + tb + dst) = hi;
            *reinterpret_cast<half8*>(Avl + tb + dst) = lo;
        }
    }
}

// ---------------------------------------------------------------------------
extern "C" void kernel_launch(void* const* d_in, const int* in_sizes, int n_in,
                              void* d_out, int out_size, void* d_ws, size_t ws_size,
                              hipStream_t stream)
{
    const float* x     = (const float*)d_in[0];
    const float* mask  = (const float*)d_in[1];
    const float* w_qkv = (const float*)d_in[2];
    const float* b_qkv = (const float*)d_in[3];
    const float* w_o   = (const float*)d_in[4];
    const float* b_o   = (const float*)d_in[5];
    float* out = (float*)d_out;

    char* p = (char*)d_ws;
    float*    Qarr = (float*)p;             p += (size_t)4096 * 1024 * 4;      // 16 MB
    _Float16* Kh   = (_Float16*)p;          p += (size_t)32 * 32 * 4096 * 2;   // 8 MB each
    _Float16* Kl   = (_Float16*)p;          p += (size_t)32 * 32 * 4096 * 2;
    _Float16* Vh   = (_Float16*)p;          p += (size_t)32 * 32 * 4096 * 2;
    _Float16* Vl   = (_Float16*)p;          p += (size_t)32 * 32 * 4096 * 2;
    _Float16* Xh   = (_Float16*)p;          p += (size_t)4096 * 1024 * 2;
    _Float16* Xl   = (_Float16*)p;          p += (size_t)4096 * 1024 * 2;
    _Float16* Wqh  = (_Float16*)p;          p += (size_t)3072 * 1024 * 2;
    _Float16* Wql  = (_Float16*)p;          p += (size_t)3072 * 1024 * 2;
    _Float16* Woh  = (_Float16*)p;          p += (size_t)1024 * 1024 * 2;
    _Float16* Wol  = (_Float16*)p;          p += (size_t)1024 * 1024 * 2;
    _Float16* Avh  = (_Float16*)p;          p += (size_t)4096 * 1024 * 2;
    _Float16* Avl  = (_Float16*)p;          p += (size_t)4096 * 1024 * 2;

    const dim3 blk(256);
    conv_hilo<<<dim3(32 * 16), blk, 0, stream>>>(x,     Xh,  Xl,  1024);
    conv_hilo<<<dim3(24 * 16), blk, 0, stream>>>(w_qkv, Wqh, Wql, 1024);
    conv_hilo<<<dim3(8 * 16),  blk, 0, stream>>>(w_o,   Woh, Wol, 1024);

    // QKV projection with fused Q/K/V epilogue
    hgemm_split<1><<<dim3(32 * 24), blk, 0, stream>>>(
        Xh, Xl, Wqh, Wql, b_qkv, nullptr, Qarr, Kh, Kl, Vh, Vl, 32, 24, 16, 3072);
    attn_mfma<<<dim3(512), blk, 0, stream>>>(Qarr, mask, Kh, Kl, Vh, Vl, Avh, Avl);
    // out projection
    hgemm_split<0><<<dim3(32 * 8), blk, 0, stream>>>(
        Avh, Avl, Woh, Wol, b_o, out, nullptr, nullptr, nullptr, nullptr, nullptr,
        32, 8, 16, 1024);
}

// Round 7
// 335.313 us; speedup vs baseline: 3.0197x; 1.0232x over previous
//
#include <hip/hip_runtime.h>
#include <cmath>

#define B_  2
#define S_  2048
#define H_  1024
#define NH_ 16
#define HD_ 64

typedef _Float16 half8  __attribute__((ext_vector_type(8)));
typedef __fp16   fp16x2 __attribute__((ext_vector_type(2)));
typedef float    f32x16 __attribute__((ext_vector_type(16)));

#define MFMA32(a, b, c) __builtin_amdgcn_mfma_f32_32x32x16_f16((a), (b), (c), 0, 0, 0)

__device__ __forceinline__ void gl2lds16(const void* g, void* l) {
    __builtin_amdgcn_global_load_lds(
        (const __attribute__((address_space(1))) unsigned int*)g,
        (__attribute__((address_space(3))) unsigned int*)l,
        16, 0, 0);
}

__device__ __forceinline__ unsigned pk16(float a, float b) {
    union { fp16x2 v; unsigned u; } c;
    c.v = __builtin_amdgcn_cvt_pkrtz(a, b);
    return c.u;
}

// hardware 2^x
__device__ __forceinline__ float exp2_hw(float x) {
#if __has_builtin(__builtin_amdgcn_exp2f)
    return __builtin_amdgcn_exp2f(x);
#else
    return __expf(x * 0.6931471805599453f);
#endif
}

#define LOG2E   1.4426950408889634f
#define SCALE_  (0.125f * LOG2E)      // 1/sqrt(64) * log2(e)
#define THR2_   11.5415603f           // 8 * log2(e)

// ---------------------------------------------------------------------------
// conv_hilo: src fp32 [R][K] -> hi/lo fp16 tiled-swizzled (128x64 tiles).
// elem (r, g*8+e) of tile at r*64 + ((g ^ (r&7))*8 + e).
// ---------------------------------------------------------------------------
__global__ __launch_bounds__(256, 4)
void conv_hilo(const float* __restrict__ src, _Float16* __restrict__ dh,
               _Float16* __restrict__ dl, int K)
{
    const int bid = blockIdx.x;
    const int nkt = K >> 6;
    const int rt  = bid / nkt;
    const int kt  = bid % nkt;
    const int tid = threadIdx.x;
    const size_t tb = (size_t)bid * 8192;
#pragma unroll
    for (int p = 0; p < 4; ++p) {
        const int idx = p * 256 + tid;
        const int r   = idx >> 3;
        const int g   = idx & 7;
        const float* s = src + (size_t)(rt * 128 + r) * K + kt * 64 + g * 8;
        const float4 v0 = *reinterpret_cast<const float4*>(s);
        const float4 v1 = *reinterpret_cast<const float4*>(s + 4);
        const float f[8] = {v0.x, v0.y, v0.z, v0.w, v1.x, v1.y, v1.z, v1.w};
        half8 hi, lo;
#pragma unroll
        for (int e = 0; e < 8; ++e) {
            const _Float16 hv = (_Float16)f[e];
            hi[e] = hv;
            lo[e] = (_Float16)(f[e] - (float)hv);
        }
        const int dst = r * 64 + ((g ^ (r & 7)) << 3);
        *reinterpret_cast<half8*>(dh + tb + dst) = hi;
        *reinterpret_cast<half8*>(dl + tb + dst) = lo;
    }
}

// ---------------------------------------------------------------------------
// Split-fp16 MFMA GEMM, 128x128 tile, BK=64, 4 waves (2x2 of 64x64).
// DOUBLE-BUFFERED: 2 x 64KB LDS buffers; next K-tile's global_load_lds are
// issued before compute on the current buffer; one barrier per K-step (its
// implicit vmcnt(0) drains the prefetch after compute has hidden it).
// QKV=0: C[m][n] = acc + bias (fp32).  QKV=1: fused epilogue writing
//   n<1024  -> Q fp32 [4096][1024]
//   n<2048  -> K hi/lo attention tiles (key*64 + (d ^ ((key&7)<<3)))
//   else    -> V^T hi/lo attention tiles (d*64 + (key ^ ((d&7)<<3)))
// ---------------------------------------------------------------------------
template<int QKV>
__global__ __launch_bounds__(256, 1)
void hgemm_split(const _Float16* __restrict__ Ah, const _Float16* __restrict__ Al,
                 const _Float16* __restrict__ Wh, const _Float16* __restrict__ Wl,
                 const float* __restrict__ bias, float* __restrict__ C,
                 float* __restrict__ Qo,
                 _Float16* __restrict__ Kh, _Float16* __restrict__ Kl,
                 _Float16* __restrict__ Vh, _Float16* __restrict__ Vl,
                 int nbm, int nbn, int nkt, int N)
{
    __shared__ __align__(16) unsigned char smem[131072];   // 2 x 64KB buffers

    const int tid  = threadIdx.x;
    const int w    = tid >> 6;
    const int lane = tid & 63;
    const int lr   = lane & 31;
    const int hh   = lane >> 5;
    const int wm   = w >> 1, wn = w & 1;

    const int nwg = nbm * nbn;
    const int cpx = nwg >> 3;
    const int bid = blockIdx.x;
    const int wg  = (bid & 7) * cpx + (bid >> 3);
    const int mt  = wg / nbn, nt = wg % nbn;

    const size_t aBase = (size_t)mt * nkt * 8192;
    const size_t wBase = (size_t)nt * nkt * 8192;

    f32x16 acc[2][2];
#pragma unroll
    for (int mi = 0; mi < 2; ++mi)
#pragma unroll
        for (int ni = 0; ni < 2; ++ni)
#pragma unroll
            for (int r = 0; r < 16; ++r) acc[mi][ni][r] = 0.f;

    // staging: 16 gl2lds16 per thread into buffer `buf`
    auto stage = [&](int kt, int buf) {
        const size_t at = aBase + (size_t)kt * 8192;
        const size_t wt = wBase + (size_t)kt * 8192;
        unsigned char* sb = smem + (buf << 16);
#pragma unroll
        for (int c = 0; c < 4; ++c) {
            const int loff = (w * 4 + c) * 512;          // halfs
            const int goff = loff + lane * 8;
            gl2lds16((const void*)(Ah + at + goff), (void*)((_Float16*)sb + loff));
            gl2lds16((const void*)(Al + at + goff), (void*)((_Float16*)(sb + 16384) + loff));
            gl2lds16((const void*)(Wh + wt + goff), (void*)((_Float16*)(sb + 32768) + loff));
            gl2lds16((const void*)(Wl + wt + goff), (void*)((_Float16*)(sb + 49152) + loff));
        }
    };

    stage(0, 0);
    __syncthreads();

    for (int kt = 0; kt < nkt; ++kt) {
        if (kt + 1 < nkt) stage(kt + 1, (kt + 1) & 1);

        unsigned char* sb = smem + ((kt & 1) << 16);
        _Float16* sAh = (_Float16*)(sb);
        _Float16* sAl = (_Float16*)(sb + 16384);
        _Float16* sWh = (_Float16*)(sb + 32768);
        _Float16* sWl = (_Float16*)(sb + 49152);

#pragma unroll
        for (int ks = 0; ks < 4; ++ks) {
            const int g = ks * 2 + hh;
            half8 aH[2], aL[2], bH[2], bL[2];
#pragma unroll
            for (int mi = 0; mi < 2; ++mi) {
                const int r   = wm * 64 + mi * 32 + lr;
                const int idx = r * 64 + ((g ^ (r & 7)) << 3);
                aH[mi] = *reinterpret_cast<const half8*>(sAh + idx);
                aL[mi] = *reinterpret_cast<const half8*>(sAl + idx);
            }
#pragma unroll
            for (int ni = 0; ni < 2; ++ni) {
                const int c   = wn * 64 + ni * 32 + lr;
                const int idx = c * 64 + ((g ^ (c & 7)) << 3);
                bH[ni] = *reinterpret_cast<const half8*>(sWh + idx);
                bL[ni] = *reinterpret_cast<const half8*>(sWl + idx);
            }
#pragma unroll
            for (int mi = 0; mi < 2; ++mi)
#pragma unroll
                for (int ni = 0; ni < 2; ++ni) {
                    acc[mi][ni] = MFMA32(aH[mi], bH[ni], acc[mi][ni]);
                    acc[mi][ni] = MFMA32(aH[mi], bL[ni], acc[mi][ni]);
                    acc[mi][ni] = MFMA32(aL[mi], bH[ni], acc[mi][ni]);
                }
        }
        __syncthreads();   // joins waves AND drains the kt+1 prefetch
    }

    if constexpr (QKV == 0) {
        const int n0 = nt * 128 + wn * 64 + lr;
        float bv[2];
#pragma unroll
        for (int ni = 0; ni < 2; ++ni) bv[ni] = bias[n0 + ni * 32];
#pragma unroll
        for (int mi = 0; mi < 2; ++mi)
#pragma unroll
            for (int ni = 0; ni < 2; ++ni)
#pragma unroll
                for (int r = 0; r < 16; ++r) {
                    const int m = mt * 128 + wm * 64 + mi * 32 +
                                  (r & 3) + 8 * (r >> 2) + 4 * hh;
                    C[(size_t)m * N + n0 + ni * 32] = acc[mi][ni][r] + bv[ni];
                }
    } else {
        // fused QKV epilogue through LDS (two 64-row passes); sC sits in buf0,
        // last compute read buf1 (nkt even) -> no aliasing hazard.
        float* sC = (float*)smem;                     // [64][132]
        const int m0  = mt * 128;
        const int b   = m0 >> 11;
        const int kt0 = (m0 & 2047) >> 6;
#pragma unroll
        for (int pass = 0; pass < 2; ++pass) {
            __syncthreads();
            if (wm == pass) {
#pragma unroll
                for (int mi = 0; mi < 2; ++mi)
#pragma unroll
                    for (int ni = 0; ni < 2; ++ni)
#pragma unroll
                        for (int r = 0; r < 16; ++r) {
                            const int ml = mi * 32 + (r & 3) + 8 * (r >> 2) + 4 * hh;
                            sC[ml * 132 + wn * 64 + ni * 32 + lr] = acc[mi][ni][r];
                        }
            }
            __syncthreads();
            const int ktile = kt0 + pass;
            if (nt < 8) {
                // Q region: fp32, coalesced
#pragma unroll
                for (int it = 0; it < 8; ++it) {
                    const int idx = it * 256 + tid;
                    const int row = idx >> 5;
                    const int c4  = (idx & 31) << 2;
                    float4 v = *reinterpret_cast<const float4*>(&sC[row * 132 + c4]);
                    const float4 bv = *reinterpret_cast<const float4*>(bias + nt * 128 + c4);
                    v.x += bv.x; v.y += bv.y; v.z += bv.z; v.w += bv.w;
                    *reinterpret_cast<float4*>(
                        Qo + (size_t)(m0 + pass * 64 + row) * 1024 + nt * 128 + c4) = v;
                }
            } else if (nt < 16) {
                // K region: hi/lo swizzled tiles
#pragma unroll
                for (int it = 0; it < 4; ++it) {
                    const int idx = it * 256 + tid;
                    const int key = idx >> 4;
                    const int g   = idx & 15;
                    const int head = 2 * (nt - 8) + (g >> 3);
                    const int d0   = (g & 7) << 3;
                    float f[8];
#pragma unroll
                    for (int e = 0; e < 8; ++e)
                        f[e] = sC[key * 132 + g * 8 + e] +
                               bias[1024 + (nt - 8) * 128 + g * 8 + e];
                    half8 hi, lo;
#pragma unroll
                    for (int e = 0; e < 8; ++e) {
                        const _Float16 hv = (_Float16)f[e];
                        hi[e] = hv;
                        lo[e] = (_Float16)(f[e] - (float)hv);
                    }
                    const size_t base = ((size_t)(b * 16 + head) * 32 + ktile) * 4096;
                    const size_t dst  = base + key * 64 + (d0 ^ ((key & 7) << 3));
                    *reinterpret_cast<half8*>(Kh + dst) = hi;
                    *reinterpret_cast<half8*>(Kl + dst) = lo;
                }
            } else {
                // V region: transposed hi/lo swizzled tiles
#pragma unroll
                for (int it = 0; it < 4; ++it) {
                    const int idx = it * 256 + tid;
                    const int f   = idx >> 3;        // feature col 0..127
                    const int kg  = idx & 7;         // key-group
                    const int head = 2 * (nt - 16) + (f >> 6);
                    const int d    = f & 63;
                    const float bv = bias[2048 + (nt - 16) * 128 + f];
                    float fe[8];
#pragma unroll
                    for (int e = 0; e < 8; ++e)
                        fe[e] = sC[(kg * 8 + e) * 132 + f] + bv;
                    half8 hi, lo;
#pragma unroll
                    for (int e = 0; e < 8; ++e) {
                        const _Float16 hv = (_Float16)fe[e];
                        hi[e] = hv;
                        lo[e] = (_Float16)(fe[e] - (float)hv);
                    }
                    const size_t base = ((size_t)(b * 16 + head) * 32 + ktile) * 4096;
                    const size_t dst  = base + d * 64 + ((kg * 8) ^ ((d & 7) << 3));
                    *reinterpret_cast<half8*>(Vh + dst) = hi;
                    *reinterpret_cast<half8*>(Vl + dst) = lo;
                }
            }
        }
    }
}

// ---------------------------------------------------------------------------
// Flash attention, split-fp16 MFMA, swapped-QK, double-buffered staging.
// Softmax in log2 domain: Q,mask pre-scaled by log2e/8; exp = v_exp_f32.
// ---------------------------------------------------------------------------
__global__ __launch_bounds__(256, 2)
void attn_mfma(const float* __restrict__ Q, const float* __restrict__ mask,
               const _Float16* __restrict__ Kh, const _Float16* __restrict__ Kl,
               const _Float16* __restrict__ Vh, const _Float16* __restrict__ Vl,
               _Float16* __restrict__ Avh, _Float16* __restrict__ Avl)
{
    __shared__ __align__(16) unsigned char smem[73728];
    // buf0 @0, buf1 @32768; within buf: Kh 0, Kl +4096, Vh +8192, Vl +12288 (halfs)
    float* sM = (float*)(smem + 65536);
    float* sO = (float*)(smem);        // epilogue alias [128][68]

    const int tid  = threadIdx.x;
    const int w    = tid >> 6;
    const int lane = tid & 63;
    const int lq   = lane & 31;
    const int hh   = lane >> 5;

    const int bid = blockIdx.x;
    const int wg  = (bid & 7) * 64 + (bid >> 3);
    const int bh  = wg >> 4;
    const int qb  = wg & 15;
    const int b   = bh >> 4, h = bh & 15;

    // mask * log2e/8 -> LDS
    {
        const float4* mg = reinterpret_cast<const float4*>(mask);
        float4* ms = reinterpret_cast<float4*>(sM);
        float4 a = mg[tid], c = mg[tid + 256];
        a.x *= SCALE_; a.y *= SCALE_; a.z *= SCALE_; a.w *= SCALE_;
        c.x *= SCALE_; c.y *= SCALE_; c.z *= SCALE_; c.w *= SCALE_;
        ms[tid] = a; ms[tid + 256] = c;
    }

    // Q fragments scaled by log2e/8, fp16 split
    const int qrow = b * S_ + qb * 128 + w * 32 + lq;
    half8 qh[4], ql[4];
#pragma unroll
    for (int ks = 0; ks < 4; ++ks) {
        const float* qp = Q + (size_t)qrow * 1024 + h * HD_ + ks * 16 + hh * 8;
        const float4 a = *reinterpret_cast<const float4*>(qp);
        const float4 c = *reinterpret_cast<const float4*>(qp + 4);
        float qf[8] = {a.x, a.y, a.z, a.w, c.x, c.y, c.z, c.w};
#pragma unroll
        for (int e = 0; e < 8; ++e) {
            const float sv = qf[e] * SCALE_;
            const _Float16 hv = (_Float16)sv;
            qh[ks][e] = hv;
            ql[ks][e] = (_Float16)(sv - (float)hv);
        }
    }

    // loop-invariant swizzled LDS offsets (shared by K and V^T reads)
    const int swz = (lq & 7) << 3;
    int off[2][4];
#pragma unroll
    for (int t2 = 0; t2 < 2; ++t2)
#pragma unroll
        for (int ks = 0; ks < 4; ++ks)
            off[t2][ks] = (t2 * 32 + lq) * 64 + ((ks * 16 + hh * 8) ^ swz);

    f32x16 o0 = {0,0,0,0,0,0,0,0,0,0,0,0,0,0,0,0};
    f32x16 o1 = {0,0,0,0,0,0,0,0,0,0,0,0,0,0,0,0};
    float m_run = -INFINITY, l_run = 0.f;

    const size_t bhbase = (size_t)bh * 32 * 4096;

    // prologue: stage tile 0 into buf0
    {
        const size_t tb = bhbase;
#pragma unroll
        for (int i = 0; i < 2; ++i) {
            const int loff = (w * 2 + i) * 512;
            const int goff = loff + lane * 8;
            _Float16* nb = (_Float16*)smem;
            gl2lds16((const void*)(Kh + tb + goff), (void*)(nb + loff));
            gl2lds16((const void*)(Kl + tb + goff), (void*)(nb + 4096 + loff));
            gl2lds16((const void*)(Vh + tb + goff), (void*)(nb + 8192 + loff));
            gl2lds16((const void*)(Vl + tb + goff), (void*)(nb + 12288 + loff));
        }
    }
    __syncthreads();

    for (int kt = 0; kt < 32; ++kt) {
        _Float16* bb = (_Float16*)(smem + ((kt & 1) << 15));
        // prefetch next tile into the other buffer
        if (kt < 31) {
            _Float16* nb = (_Float16*)(smem + (((kt + 1) & 1) << 15));
            const size_t tb = bhbase + (size_t)(kt + 1) * 4096;
#pragma unroll
            for (int i = 0; i < 2; ++i) {
                const int loff = (w * 2 + i) * 512;
                const int goff = loff + lane * 8;
                gl2lds16((const void*)(Kh + tb + goff), (void*)(nb + loff));
                gl2lds16((const void*)(Kl + tb + goff), (void*)(nb + 4096 + loff));
                gl2lds16((const void*)(Vh + tb + goff), (void*)(nb + 8192 + loff));
                gl2lds16((const void*)(Vl + tb + goff), (void*)(nb + 12288 + loff));
            }
        }

        // ---- S^T = K Q^T (3-term split) ----
        f32x16 st[2];
#pragma unroll
        for (int ktt = 0; ktt < 2; ++ktt) {
            f32x16 acc = {0,0,0,0,0,0,0,0,0,0,0,0,0,0,0,0};
#pragma unroll
            for (int ks = 0; ks < 4; ++ks) {
                const half8 ka = *reinterpret_cast<const half8*>(bb + off[ktt][ks]);
                const half8 kb = *reinterpret_cast<const half8*>(bb + 4096 + off[ktt][ks]);
                acc = MFMA32(ka, qh[ks], acc);
                acc = MFMA32(ka, ql[ks], acc);
                acc = MFMA32(kb, qh[ks], acc);
            }
            st[ktt] = acc;
        }

        // ---- + mask (pre-scaled), running max (all in log2 units) ----
        float mx = -INFINITY;
#pragma unroll
        for (int ktt = 0; ktt < 2; ++ktt) {
#pragma unroll
            for (int rr = 0; rr < 4; ++rr) {
                const int key0 = kt * 64 + ktt * 32 + rr * 8 + hh * 4;
                const float4 mk = *reinterpret_cast<const float4*>(sM + key0);
                const float mkv[4] = {mk.x, mk.y, mk.z, mk.w};
#pragma unroll
                for (int c = 0; c < 4; ++c) {
                    const int r = rr * 4 + c;
                    const float tv = st[ktt][r] + mkv[c];
                    st[ktt][r] = tv;
                    mx = fmaxf(mx, tv);
                }
            }
        }
        mx = fmaxf(mx, __shfl_xor(mx, 32));

        // ---- defer-max online softmax (T13, THR=8 in nat units) ----
        if (!__all(mx - m_run <= THR2_)) {
            const float mnew = fmaxf(m_run, mx);
            const float corr = exp2_hw(m_run - mnew);
            m_run = mnew;
            l_run *= corr;
#pragma unroll
            for (int r = 0; r < 16; ++r) { o0[r] *= corr; o1[r] *= corr; }
        }
        float ps = 0.f;
#pragma unroll
        for (int ktt = 0; ktt < 2; ++ktt)
#pragma unroll
            for (int r = 0; r < 16; ++r) {
                const float p = exp2_hw(st[ktt][r] - m_run);
                st[ktt][r] = p;
                ps += p;
            }
        ps += __shfl_xor(ps, 32);
        l_run += ps;

        // ---- pack P hi/lo via pkrtz ----
        unsigned wph[2][4][2], wpl[2][4][2];
#pragma unroll
        for (int ktt = 0; ktt < 2; ++ktt)
#pragma unroll
            for (int rr = 0; rr < 4; ++rr)
#pragma unroll
                for (int pp = 0; pp < 2; ++pp) {
                    const float p0 = st[ktt][rr * 4 + pp * 2 + 0];
                    const float p1 = st[ktt][rr * 4 + pp * 2 + 1];
                    union { fp16x2 v; unsigned u; } hw;
                    hw.v = __builtin_amdgcn_cvt_pkrtz(p0, p1);
                    wph[ktt][rr][pp] = hw.u;
                    wpl[ktt][rr][pp] = pk16(p0 - (float)hw.v[0], p1 - (float)hw.v[1]);
                }

        // ---- assemble P B-frags via shfl_xor(32); O^T += V^T P^T ----
#pragma unroll
        for (int ks = 0; ks < 4; ++ks) {
            const int i1 = ks >> 1;
            const int rA = (ks & 1) * 2;
            union { unsigned u[4]; half8 v; } ph, pl;
            {
                const unsigned oA0 = wph[i1][rA + 0][0], oB0 = wph[i1][rA + 0][1];
                const unsigned oA1 = wph[i1][rA + 1][0], oB1 = wph[i1][rA + 1][1];
                const unsigned sA1 = (unsigned)__shfl_xor((int)oA1, 32);
                const unsigned sB1 = (unsigned)__shfl_xor((int)oB1, 32);
                const unsigned sA0 = (unsigned)__shfl_xor((int)oA0, 32);
                const unsigned sB0 = (unsigned)__shfl_xor((int)oB0, 32);
                ph.u[0] = hh ? sA1 : oA0;
                ph.u[1] = hh ? sB1 : oB0;
                ph.u[2] = hh ? oA1 : sA0;
                ph.u[3] = hh ? oB1 : sB0;
            }
            {
                const unsigned oA0 = wpl[i1][rA + 0][0], oB0 = wpl[i1][rA + 0][1];
                const unsigned oA1 = wpl[i1][rA + 1][0], oB1 = wpl[i1][rA + 1][1];
                const unsigned sA1 = (unsigned)__shfl_xor((int)oA1, 32);
                const unsigned sB1 = (unsigned)__shfl_xor((int)oB1, 32);
                const unsigned sA0 = (unsigned)__shfl_xor((int)oA0, 32);
                const unsigned sB0 = (unsigned)__shfl_xor((int)oB0, 32);
                pl.u[0] = hh ? sA1 : oA0;
                pl.u[1] = hh ? sB1 : oB0;
                pl.u[2] = hh ? oA1 : sA0;
                pl.u[3] = hh ? oB1 : sB0;
            }
#pragma unroll
            for (int dt = 0; dt < 2; ++dt) {
                const half8 va = *reinterpret_cast<const half8*>(bb + 8192 + off[dt][ks]);
                const half8 vb = *reinterpret_cast<const half8*>(bb + 12288 + off[dt][ks]);
                if (dt == 0) {
                    o0 = MFMA32(va, ph.v, o0);
                    o0 = MFMA32(va, pl.v, o0);
                    o0 = MFMA32(vb, ph.v, o0);
                } else {
                    o1 = MFMA32(va, ph.v, o1);
                    o1 = MFMA32(va, pl.v, o1);
                    o1 = MFMA32(vb, ph.v, o1);
                }
            }
        }
        __syncthreads();   // joins waves AND drains the kt+1 prefetch
    }

    // ---- epilogue: normalize, LDS transpose, emit hi/lo swizzled Av tile ----
    const float inv = 1.f / l_run;
#pragma unroll
    for (int dt = 0; dt < 2; ++dt)
#pragma unroll
        for (int r = 0; r < 16; ++r) {
            const int d = dt * 32 + (r & 3) + 8 * (r >> 2) + 4 * hh;
            sO[(w * 32 + lq) * 68 + d] = (dt ? o1[r] : o0[r]) * inv;
        }
    __syncthreads();
    {
        const size_t tb = (((size_t)(b * 16 + qb)) * 16 + h) * 8192;
#pragma unroll
        for (int p = 0; p < 4; ++p) {
            const int idx = p * 256 + tid;
            const int q = idx >> 3, g = idx & 7;
            const float4 v0 = *reinterpret_cast<const float4*>(&sO[q * 68 + g * 8]);
            const float4 v1 = *reinterpret_cast<const float4*>(&sO[q * 68 + g * 8 + 4]);
            const float f[8] = {v0.x, v0.y, v0.z, v0.w, v1.x, v1.y, v1.z, v1.w};
            half8 hi, lo;
#pragma unroll
            for (int e = 0; e < 8; ++e) {
                const _Float16 hv = (_Float16)f[e];
                hi[e] = hv;
                lo[e] = (_Float16)(f[e] - (float)hv);
            }
            const int dst = q * 64 + ((g ^ (q & 7)) << 3);
            *reinterpret_cast<half8*>(Avh + tb + dst) = hi;
            *reinterpret_cast<half8*>(Avl + tb + dst) = lo;
        }
    }
}

// ---------------------------------------------------------------------------
extern "C" void kernel_launch(void* const* d_in, const int* in_sizes, int n_in,
                              void* d_out, int out_size, void* d_ws, size_t ws_size,
                              hipStream_t stream)
{
    const float* x     = (const float*)d_in[0];
    const float* mask  = (const float*)d_in[1];
    const float* w_qkv = (const float*)d_in[2];
    const float* b_qkv = (const float*)d_in[3];
    const float* w_o   = (const float*)d_in[4];
    const float* b_o   = (const float*)d_in[5];
    float* out = (float*)d_out;

    char* p = (char*)d_ws;
    float*    Qarr = (float*)p;             p += (size_t)4096 * 1024 * 4;      // 16 MB
    _Float16* Kh   = (_Float16*)p;          p += (size_t)32 * 32 * 4096 * 2;   // 8 MB each
    _Float16* Kl   = (_Float16*)p;          p += (size_t)32 * 32 * 4096 * 2;
    _Float16* Vh   = (_Float16*)p;          p += (size_t)32 * 32 * 4096 * 2;
    _Float16* Vl   = (_Float16*)p;          p += (size_t)32 * 32 * 4096 * 2;
    _Float16* Xh   = (_Float16*)p;          p += (size_t)4096 * 1024 * 2;
    _Float16* Xl   = (_Float16*)p;          p += (size_t)4096 * 1024 * 2;
    _Float16* Wqh  = (_Float16*)p;          p += (size_t)3072 * 1024 * 2;
    _Float16* Wql  = (_Float16*)p;          p += (size_t)3072 * 1024 * 2;
    _Float16* Woh  = (_Float16*)p;          p += (size_t)1024 * 1024 * 2;
    _Float16* Wol  = (_Float16*)p;          p += (size_t)1024 * 1024 * 2;
    _Float16* Avh  = (_Float16*)p;          p += (size_t)4096 * 1024 * 2;
    _Float16* Avl  = (_Float16*)p;          p += (size_t)4096 * 1024 * 2;

    const dim3 blk(256);
    conv_hilo<<<dim3(32 * 16), blk, 0, stream>>>(x,     Xh,  Xl,  1024);
    conv_hilo<<<dim3(24 * 16), blk, 0, stream>>>(w_qkv, Wqh, Wql, 1024);
    conv_hilo<<<dim3(8 * 16),  blk, 0, stream>>>(w_o,   Woh, Wol, 1024);

    // QKV projection with fused Q/K/V epilogue
    hgemm_split<1><<<dim3(32 * 24), blk, 0, stream>>>(
        Xh, Xl, Wqh, Wql, b_qkv, nullptr, Qarr, Kh, Kl, Vh, Vl, 32, 24, 16, 3072);
    attn_mfma<<<dim3(512), blk, 0, stream>>>(Qarr, mask, Kh, Kl, Vh, Vl, Avh, Avl);
    // out projection
    hgemm_split<0><<<dim3(32 * 8), blk, 0, stream>>>(
        Avh, Avl, Woh, Wol, b_o, out, nullptr, nullptr, nullptr, nullptr, nullptr,
        32, 8, 16, 1024);
}

// Round 8
// 319.521 us; speedup vs baseline: 3.1690x; 1.0494x over previous
//
#include <hip/hip_runtime.h>
#include <cmath>

#define B_  2
#define S_  2048
#define H_  1024
#define NH_ 16
#define HD_ 64

typedef _Float16 half8  __attribute__((ext_vector_type(8)));
typedef __fp16   fp16x2 __attribute__((ext_vector_type(2)));
typedef float    f32x16 __attribute__((ext_vector_type(16)));

#define MFMA32(a, b, c) __builtin_amdgcn_mfma_f32_32x32x16_f16((a), (b), (c), 0, 0, 0)

__device__ __forceinline__ void gl2lds16(const void* g, void* l) {
    __builtin_amdgcn_global_load_lds(
        (const __attribute__((address_space(1))) unsigned int*)g,
        (__attribute__((address_space(3))) unsigned int*)l,
        16, 0, 0);
}

__device__ __forceinline__ unsigned pk16(float a, float b) {
    union { fp16x2 v; unsigned u; } c;
    c.v = __builtin_amdgcn_cvt_pkrtz(a, b);
    return c.u;
}

// hardware 2^x
__device__ __forceinline__ float exp2_hw(float x) {
#if __has_builtin(__builtin_amdgcn_exp2f)
    return __builtin_amdgcn_exp2f(x);
#else
    return __expf(x * 0.6931471805599453f);
#endif
}

#define LOG2E   1.4426950408889634f
#define SCALE_  (0.125f * LOG2E)      // 1/sqrt(64) * log2(e)
#define THR2_   11.5415603f           // 8 * log2(e)

// ---------------------------------------------------------------------------
// conv_hilo: src fp32 [R][K] -> hi/lo fp16 tiled-swizzled (128x64 tiles).
// elem (r, g*8+e) of tile at r*64 + ((g ^ (r&7))*8 + e).
// ---------------------------------------------------------------------------
__global__ __launch_bounds__(256, 4)
void conv_hilo(const float* __restrict__ src, _Float16* __restrict__ dh,
               _Float16* __restrict__ dl, int K)
{
    const int bid = blockIdx.x;
    const int nkt = K >> 6;
    const int rt  = bid / nkt;
    const int kt  = bid % nkt;
    const int tid = threadIdx.x;
    const size_t tb = (size_t)bid * 8192;
#pragma unroll
    for (int p = 0; p < 4; ++p) {
        const int idx = p * 256 + tid;
        const int r   = idx >> 3;
        const int g   = idx & 7;
        const float* s = src + (size_t)(rt * 128 + r) * K + kt * 64 + g * 8;
        const float4 v0 = *reinterpret_cast<const float4*>(s);
        const float4 v1 = *reinterpret_cast<const float4*>(s + 4);
        const float f[8] = {v0.x, v0.y, v0.z, v0.w, v1.x, v1.y, v1.z, v1.w};
        half8 hi, lo;
#pragma unroll
        for (int e = 0; e < 8; ++e) {
            const _Float16 hv = (_Float16)f[e];
            hi[e] = hv;
            lo[e] = (_Float16)(f[e] - (float)hv);
        }
        const int dst = r * 64 + ((g ^ (r & 7)) << 3);
        *reinterpret_cast<half8*>(dh + tb + dst) = hi;
        *reinterpret_cast<half8*>(dl + tb + dst) = lo;
    }
}

// ---------------------------------------------------------------------------
// Split-fp16 MFMA GEMM, 128x128 tile, BK=64, 8 waves (4x2 of 32x64 sub-tiles),
// 512 threads, double-buffered (2 x 64KB LDS), 2 waves/SIMD for overlap.
// QKV=0: C[m][n] = acc + bias (fp32).  QKV=1: fused epilogue writing
//   n<1024  -> Q fp32 [4096][1024]
//   n<2048  -> K hi/lo attention tiles (key*64 + (d ^ ((key&7)<<3)))
//   else    -> V^T hi/lo attention tiles (d*64 + (key ^ ((d&7)<<3)))
// ---------------------------------------------------------------------------
template<int QKV>
__global__ __launch_bounds__(512, 1)
void hgemm_split(const _Float16* __restrict__ Ah, const _Float16* __restrict__ Al,
                 const _Float16* __restrict__ Wh, const _Float16* __restrict__ Wl,
                 const float* __restrict__ bias, float* __restrict__ C,
                 float* __restrict__ Qo,
                 _Float16* __restrict__ Kh, _Float16* __restrict__ Kl,
                 _Float16* __restrict__ Vh, _Float16* __restrict__ Vl,
                 int nbm, int nbn, int nkt, int N)
{
    __shared__ __align__(16) unsigned char smem[131072];   // 2 x 64KB buffers

    const int tid  = threadIdx.x;
    const int w    = tid >> 6;        // 0..7
    const int lane = tid & 63;
    const int lr   = lane & 31;
    const int hh   = lane >> 5;
    const int wm   = w >> 1;          // 0..3 : 32-row strip
    const int wn   = w & 1;           // 0..1 : 64-col half

    const int nwg = nbm * nbn;
    const int cpx = nwg >> 3;
    const int bid = blockIdx.x;
    const int wg  = (bid & 7) * cpx + (bid >> 3);
    const int mt  = wg / nbn, nt = wg % nbn;

    const size_t aBase = (size_t)mt * nkt * 8192;
    const size_t wBase = (size_t)nt * nkt * 8192;

    f32x16 acc[2];
#pragma unroll
    for (int ni = 0; ni < 2; ++ni)
#pragma unroll
        for (int r = 0; r < 16; ++r) acc[ni][r] = 0.f;

    // staging: 8 gl2lds16 per thread into buffer `buf`
    auto stage = [&](int kt, int buf) {
        const size_t at = aBase + (size_t)kt * 8192;
        const size_t wt = wBase + (size_t)kt * 8192;
        unsigned char* sb = smem + (buf << 16);
#pragma unroll
        for (int c = 0; c < 2; ++c) {
            const int off = (c * 512 + tid) * 8;         // halfs, linear
            gl2lds16((const void*)(Ah + at + off), (void*)((_Float16*)sb + off));
            gl2lds16((const void*)(Al + at + off), (void*)((_Float16*)(sb + 16384) + off));
            gl2lds16((const void*)(Wh + wt + off), (void*)((_Float16*)(sb + 32768) + off));
            gl2lds16((const void*)(Wl + wt + off), (void*)((_Float16*)(sb + 49152) + off));
        }
    };

    stage(0, 0);
    __syncthreads();

    for (int kt = 0; kt < nkt; ++kt) {
        if (kt + 1 < nkt) stage(kt + 1, (kt + 1) & 1);

        unsigned char* sb = smem + ((kt & 1) << 16);
        _Float16* sAh = (_Float16*)(sb);
        _Float16* sAl = (_Float16*)(sb + 16384);
        _Float16* sWh = (_Float16*)(sb + 32768);
        _Float16* sWl = (_Float16*)(sb + 49152);

#pragma unroll
        for (int ks = 0; ks < 4; ++ks) {
            const int g = ks * 2 + hh;
            const int r = wm * 32 + lr;
            const int aidx = r * 64 + ((g ^ (r & 7)) << 3);
            const half8 aH = *reinterpret_cast<const half8*>(sAh + aidx);
            const half8 aL = *reinterpret_cast<const half8*>(sAl + aidx);
            half8 bH[2], bL[2];
#pragma unroll
            for (int ni = 0; ni < 2; ++ni) {
                const int c   = wn * 64 + ni * 32 + lr;
                const int idx = c * 64 + ((g ^ (c & 7)) << 3);
                bH[ni] = *reinterpret_cast<const half8*>(sWh + idx);
                bL[ni] = *reinterpret_cast<const half8*>(sWl + idx);
            }
#pragma unroll
            for (int ni = 0; ni < 2; ++ni) {
                acc[ni] = MFMA32(aH, bH[ni], acc[ni]);
                acc[ni] = MFMA32(aH, bL[ni], acc[ni]);
                acc[ni] = MFMA32(aL, bH[ni], acc[ni]);
            }
        }
        __syncthreads();   // joins waves AND drains the kt+1 prefetch
    }

    if constexpr (QKV == 0) {
        const int n0 = nt * 128 + wn * 64 + lr;
        float bv[2];
#pragma unroll
        for (int ni = 0; ni < 2; ++ni) bv[ni] = bias[n0 + ni * 32];
#pragma unroll
        for (int ni = 0; ni < 2; ++ni)
#pragma unroll
            for (int r = 0; r < 16; ++r) {
                const int m = mt * 128 + wm * 32 + (r & 3) + 8 * (r >> 2) + 4 * hh;
                C[(size_t)m * N + n0 + ni * 32] = acc[ni][r] + bv[ni];
            }
    } else {
        // fused QKV epilogue through LDS (two 64-row passes); sC in buf0,
        // last compute read buf1 (nkt even) -> no aliasing hazard.
        float* sC = (float*)smem;                     // [64][132]
        const int m0  = mt * 128;
        const int b   = m0 >> 11;
        const int kt0 = (m0 & 2047) >> 6;
#pragma unroll
        for (int pass = 0; pass < 2; ++pass) {
            __syncthreads();
            if ((wm >> 1) == pass) {
#pragma unroll
                for (int ni = 0; ni < 2; ++ni)
#pragma unroll
                    for (int r = 0; r < 16; ++r) {
                        const int ml = (wm & 1) * 32 + (r & 3) + 8 * (r >> 2) + 4 * hh;
                        sC[ml * 132 + wn * 64 + ni * 32 + lr] = acc[ni][r];
                    }
            }
            __syncthreads();
            const int ktile = kt0 + pass;
            if (nt < 8) {
                // Q region: fp32, coalesced
#pragma unroll
                for (int it = 0; it < 4; ++it) {
                    const int idx = it * 512 + tid;
                    const int row = idx >> 5;
                    const int c4  = (idx & 31) << 2;
                    float4 v = *reinterpret_cast<const float4*>(&sC[row * 132 + c4]);
                    const float4 bv = *reinterpret_cast<const float4*>(bias + nt * 128 + c4);
                    v.x += bv.x; v.y += bv.y; v.z += bv.z; v.w += bv.w;
                    *reinterpret_cast<float4*>(
                        Qo + (size_t)(m0 + pass * 64 + row) * 1024 + nt * 128 + c4) = v;
                }
            } else if (nt < 16) {
                // K region: hi/lo swizzled tiles
#pragma unroll
                for (int it = 0; it < 2; ++it) {
                    const int idx = it * 512 + tid;
                    const int key = idx >> 4;
                    const int g   = idx & 15;
                    const int head = 2 * (nt - 8) + (g >> 3);
                    const int d0   = (g & 7) << 3;
                    float f[8];
#pragma unroll
                    for (int e = 0; e < 8; ++e)
                        f[e] = sC[key * 132 + g * 8 + e] +
                               bias[1024 + (nt - 8) * 128 + g * 8 + e];
                    half8 hi, lo;
#pragma unroll
                    for (int e = 0; e < 8; ++e) {
                        const _Float16 hv = (_Float16)f[e];
                        hi[e] = hv;
                        lo[e] = (_Float16)(f[e] - (float)hv);
                    }
                    const size_t base = ((size_t)(b * 16 + head) * 32 + ktile) * 4096;
                    const size_t dst  = base + key * 64 + (d0 ^ ((key & 7) << 3));
                    *reinterpret_cast<half8*>(Kh + dst) = hi;
                    *reinterpret_cast<half8*>(Kl + dst) = lo;
                }
            } else {
                // V region: transposed hi/lo swizzled tiles
#pragma unroll
                for (int it = 0; it < 2; ++it) {
                    const int idx = it * 512 + tid;
                    const int f   = idx >> 3;        // feature col 0..127
                    const int kg  = idx & 7;         // key-group
                    const int head = 2 * (nt - 16) + (f >> 6);
                    const int d    = f & 63;
                    const float bv = bias[2048 + (nt - 16) * 128 + f];
                    float fe[8];
#pragma unroll
                    for (int e = 0; e < 8; ++e)
                        fe[e] = sC[(kg * 8 + e) * 132 + f] + bv;
                    half8 hi, lo;
#pragma unroll
                    for (int e = 0; e < 8; ++e) {
                        const _Float16 hv = (_Float16)fe[e];
                        hi[e] = hv;
                        lo[e] = (_Float16)(fe[e] - (float)hv);
                    }
                    const size_t base = ((size_t)(b * 16 + head) * 32 + ktile) * 4096;
                    const size_t dst  = base + d * 64 + ((kg * 8) ^ ((d & 7) << 3));
                    *reinterpret_cast<half8*>(Vh + dst) = hi;
                    *reinterpret_cast<half8*>(Vl + dst) = lo;
                }
            }
        }
    }
}

// ---------------------------------------------------------------------------
// Flash attention, split-fp16 MFMA, swapped-QK, double-buffered staging.
// QK^T: 3-term split. PV: 2-term (Ph*Vh + Ph*Vl) -- Pl*Vh dropped, error
// ~2^-11/sqrt(l) < 2e-4. Softmax in log2 domain.
// ---------------------------------------------------------------------------
__global__ __launch_bounds__(256, 2)
void attn_mfma(const float* __restrict__ Q, const float* __restrict__ mask,
               const _Float16* __restrict__ Kh, const _Float16* __restrict__ Kl,
               const _Float16* __restrict__ Vh, const _Float16* __restrict__ Vl,
               _Float16* __restrict__ Avh, _Float16* __restrict__ Avl)
{
    __shared__ __align__(16) unsigned char smem[73728];
    // buf0 @0, buf1 @32768; within buf: Kh 0, Kl +4096, Vh +8192, Vl +12288 (halfs)
    float* sM = (float*)(smem + 65536);
    float* sO = (float*)(smem);        // epilogue alias [128][68]

    const int tid  = threadIdx.x;
    const int w    = tid >> 6;
    const int lane = tid & 63;
    const int lq   = lane & 31;
    const int hh   = lane >> 5;

    const int bid = blockIdx.x;
    const int wg  = (bid & 7) * 64 + (bid >> 3);
    const int bh  = wg >> 4;
    const int qb  = wg & 15;
    const int b   = bh >> 4, h = bh & 15;

    // mask * log2e/8 -> LDS
    {
        const float4* mg = reinterpret_cast<const float4*>(mask);
        float4* ms = reinterpret_cast<float4*>(sM);
        float4 a = mg[tid], c = mg[tid + 256];
        a.x *= SCALE_; a.y *= SCALE_; a.z *= SCALE_; a.w *= SCALE_;
        c.x *= SCALE_; c.y *= SCALE_; c.z *= SCALE_; c.w *= SCALE_;
        ms[tid] = a; ms[tid + 256] = c;
    }

    // Q fragments scaled by log2e/8, fp16 split
    const int qrow = b * S_ + qb * 128 + w * 32 + lq;
    half8 qh[4], ql[4];
#pragma unroll
    for (int ks = 0; ks < 4; ++ks) {
        const float* qp = Q + (size_t)qrow * 1024 + h * HD_ + ks * 16 + hh * 8;
        const float4 a = *reinterpret_cast<const float4*>(qp);
        const float4 c = *reinterpret_cast<const float4*>(qp + 4);
        float qf[8] = {a.x, a.y, a.z, a.w, c.x, c.y, c.z, c.w};
#pragma unroll
        for (int e = 0; e < 8; ++e) {
            const float sv = qf[e] * SCALE_;
            const _Float16 hv = (_Float16)sv;
            qh[ks][e] = hv;
            ql[ks][e] = (_Float16)(sv - (float)hv);
        }
    }

    // loop-invariant swizzled LDS offsets (shared by K and V^T reads)
    const int swz = (lq & 7) << 3;
    int off[2][4];
#pragma unroll
    for (int t2 = 0; t2 < 2; ++t2)
#pragma unroll
        for (int ks = 0; ks < 4; ++ks)
            off[t2][ks] = (t2 * 32 + lq) * 64 + ((ks * 16 + hh * 8) ^ swz);

    f32x16 o0 = {0,0,0,0,0,0,0,0,0,0,0,0,0,0,0,0};
    f32x16 o1 = {0,0,0,0,0,0,0,0,0,0,0,0,0,0,0,0};
    float m_run = -INFINITY, l_run = 0.f;

    const size_t bhbase = (size_t)bh * 32 * 4096;

    // prologue: stage tile 0 into buf0
    {
        const size_t tb = bhbase;
#pragma unroll
        for (int i = 0; i < 2; ++i) {
            const int loff = (w * 2 + i) * 512;
            const int goff = loff + lane * 8;
            _Float16* nb = (_Float16*)smem;
            gl2lds16((const void*)(Kh + tb + goff), (void*)(nb + loff));
            gl2lds16((const void*)(Kl + tb + goff), (void*)(nb + 4096 + loff));
            gl2lds16((const void*)(Vh + tb + goff), (void*)(nb + 8192 + loff));
            gl2lds16((const void*)(Vl + tb + goff), (void*)(nb + 12288 + loff));
        }
    }
    __syncthreads();

    for (int kt = 0; kt < 32; ++kt) {
        _Float16* bb = (_Float16*)(smem + ((kt & 1) << 15));
        // prefetch next tile into the other buffer
        if (kt < 31) {
            _Float16* nb = (_Float16*)(smem + (((kt + 1) & 1) << 15));
            const size_t tb = bhbase + (size_t)(kt + 1) * 4096;
#pragma unroll
            for (int i = 0; i < 2; ++i) {
                const int loff = (w * 2 + i) * 512;
                const int goff = loff + lane * 8;
                gl2lds16((const void*)(Kh + tb + goff), (void*)(nb + loff));
                gl2lds16((const void*)(Kl + tb + goff), (void*)(nb + 4096 + loff));
                gl2lds16((const void*)(Vh + tb + goff), (void*)(nb + 8192 + loff));
                gl2lds16((const void*)(Vl + tb + goff), (void*)(nb + 12288 + loff));
            }
        }

        // ---- S^T = K Q^T (3-term split) ----
        f32x16 st[2];
#pragma unroll
        for (int ktt = 0; ktt < 2; ++ktt) {
            f32x16 acc = {0,0,0,0,0,0,0,0,0,0,0,0,0,0,0,0};
#pragma unroll
            for (int ks = 0; ks < 4; ++ks) {
                const half8 ka = *reinterpret_cast<const half8*>(bb + off[ktt][ks]);
                const half8 kb = *reinterpret_cast<const half8*>(bb + 4096 + off[ktt][ks]);
                acc = MFMA32(ka, qh[ks], acc);
                acc = MFMA32(ka, ql[ks], acc);
                acc = MFMA32(kb, qh[ks], acc);
            }
            st[ktt] = acc;
        }

        // ---- + mask (pre-scaled), running max (log2 units) ----
        float mx = -INFINITY;
#pragma unroll
        for (int ktt = 0; ktt < 2; ++ktt) {
#pragma unroll
            for (int rr = 0; rr < 4; ++rr) {
                const int key0 = kt * 64 + ktt * 32 + rr * 8 + hh * 4;
                const float4 mk = *reinterpret_cast<const float4*>(sM + key0);
                const float mkv[4] = {mk.x, mk.y, mk.z, mk.w};
#pragma unroll
                for (int c = 0; c < 4; ++c) {
                    const int r = rr * 4 + c;
                    const float tv = st[ktt][r] + mkv[c];
                    st[ktt][r] = tv;
                    mx = fmaxf(mx, tv);
                }
            }
        }
        mx = fmaxf(mx, __shfl_xor(mx, 32));

        // ---- defer-max online softmax (T13) ----
        if (!__all(mx - m_run <= THR2_)) {
            const float mnew = fmaxf(m_run, mx);
            const float corr = exp2_hw(m_run - mnew);
            m_run = mnew;
            l_run *= corr;
#pragma unroll
            for (int r = 0; r < 16; ++r) { o0[r] *= corr; o1[r] *= corr; }
        }
        float ps = 0.f;
#pragma unroll
        for (int ktt = 0; ktt < 2; ++ktt)
#pragma unroll
            for (int r = 0; r < 16; ++r) {
                const float p = exp2_hw(st[ktt][r] - m_run);
                st[ktt][r] = p;
                ps += p;
            }
        ps += __shfl_xor(ps, 32);
        l_run += ps;

        // ---- pack P hi via pkrtz (Pl dropped) ----
        unsigned wph[2][4][2];
#pragma unroll
        for (int ktt = 0; ktt < 2; ++ktt)
#pragma unroll
            for (int rr = 0; rr < 4; ++rr)
#pragma unroll
                for (int pp = 0; pp < 2; ++pp)
                    wph[ktt][rr][pp] = pk16(st[ktt][rr * 4 + pp * 2 + 0],
                                            st[ktt][rr * 4 + pp * 2 + 1]);

        // ---- assemble P B-frags via shfl_xor(32); O^T += V^T P^T (2-term) ----
#pragma unroll
        for (int ks = 0; ks < 4; ++ks) {
            const int i1 = ks >> 1;
            const int rA = (ks & 1) * 2;
            union { unsigned u[4]; half8 v; } ph;
            {
                const unsigned oA0 = wph[i1][rA + 0][0], oB0 = wph[i1][rA + 0][1];
                const unsigned oA1 = wph[i1][rA + 1][0], oB1 = wph[i1][rA + 1][1];
                const unsigned sA1 = (unsigned)__shfl_xor((int)oA1, 32);
                const unsigned sB1 = (unsigned)__shfl_xor((int)oB1, 32);
                const unsigned sA0 = (unsigned)__shfl_xor((int)oA0, 32);
                const unsigned sB0 = (unsigned)__shfl_xor((int)oB0, 32);
                ph.u[0] = hh ? sA1 : oA0;
                ph.u[1] = hh ? sB1 : oB0;
                ph.u[2] = hh ? oA1 : sA0;
                ph.u[3] = hh ? oB1 : sB0;
            }
#pragma unroll
            for (int dt = 0; dt < 2; ++dt) {
                const half8 va = *reinterpret_cast<const half8*>(bb + 8192 + off[dt][ks]);
                const half8 vb = *reinterpret_cast<const half8*>(bb + 12288 + off[dt][ks]);
                if (dt == 0) {
                    o0 = MFMA32(va, ph.v, o0);
                    o0 = MFMA32(vb, ph.v, o0);
                } else {
                    o1 = MFMA32(va, ph.v, o1);
                    o1 = MFMA32(vb, ph.v, o1);
                }
            }
        }
        __syncthreads();   // joins waves AND drains the kt+1 prefetch
    }

    // ---- epilogue: normalize, LDS transpose, emit hi/lo swizzled Av tile ----
    const float inv = 1.f / l_run;
#pragma unroll
    for (int dt = 0; dt < 2; ++dt)
#pragma unroll
        for (int r = 0; r < 16; ++r) {
            const int d = dt * 32 + (r & 3) + 8 * (r >> 2) + 4 * hh;
            sO[(w * 32 + lq) * 68 + d] = (dt ? o1[r] : o0[r]) * inv;
        }
    __syncthreads();
    {
        const size_t tb = (((size_t)(b * 16 + qb)) * 16 + h) * 8192;
#pragma unroll
        for (int p = 0; p < 4; ++p) {
            const int idx = p * 256 + tid;
            const int q = idx >> 3, g = idx & 7;
            const float4 v0 = *reinterpret_cast<const float4*>(&sO[q * 68 + g * 8]);
            const float4 v1 = *reinterpret_cast<const float4*>(&sO[q * 68 + g * 8 + 4]);
            const float f[8] = {v0.x, v0.y, v0.z, v0.w, v1.x, v1.y, v1.z, v1.w};
            half8 hi, lo;
#pragma unroll
            for (int e = 0; e < 8; ++e) {
                const _Float16 hv = (_Float16)f[e];
                hi[e] = hv;
                lo[e] = (_Float16)(f[e] - (float)hv);
            }
            const int dst = q * 64 + ((g ^ (q & 7)) << 3);
            *reinterpret_cast<half8*>(Avh + tb + dst) = hi;
            *reinterpret_cast<half8*>(Avl + tb + dst) = lo;
        }
    }
}

// ---------------------------------------------------------------------------
extern "C" void kernel_launch(void* const* d_in, const int* in_sizes, int n_in,
                              void* d_out, int out_size, void* d_ws, size_t ws_size,
                              hipStream_t stream)
{
    const float* x     = (const float*)d_in[0];
    const float* mask  = (const float*)d_in[1];
    const float* w_qkv = (const float*)d_in[2];
    const float* b_qkv = (const float*)d_in[3];
    const float* w_o   = (const float*)d_in[4];
    const float* b_o   = (const float*)d_in[5];
    float* out = (float*)d_out;

    char* p = (char*)d_ws;
    float*    Qarr = (float*)p;             p += (size_t)4096 * 1024 * 4;      // 16 MB
    _Float16* Kh   = (_Float16*)p;          p += (size_t)32 * 32 * 4096 * 2;   // 8 MB each
    _Float16* Kl   = (_Float16*)p;          p += (size_t)32 * 32 * 4096 * 2;
    _Float16* Vh   = (_Float16*)p;          p += (size_t)32 * 32 * 4096 * 2;
    _Float16* Vl   = (_Float16*)p;          p += (size_t)32 * 32 * 4096 * 2;
    _Float16* Xh   = (_Float16*)p;          p += (size_t)4096 * 1024 * 2;
    _Float16* Xl   = (_Float16*)p;          p += (size_t)4096 * 1024 * 2;
    _Float16* Wqh  = (_Float16*)p;          p += (size_t)3072 * 1024 * 2;
    _Float16* Wql  = (_Float16*)p;          p += (size_t)3072 * 1024 * 2;
    _Float16* Woh  = (_Float16*)p;          p += (size_t)1024 * 1024 * 2;
    _Float16* Wol  = (_Float16*)p;          p += (size_t)1024 * 1024 * 2;
    _Float16* Avh  = (_Float16*)p;          p += (size_t)4096 * 1024 * 2;
    _Float16* Avl  = (_Float16*)p;          p += (size_t)4096 * 1024 * 2;

    conv_hilo<<<dim3(32 * 16), dim3(256), 0, stream>>>(x,     Xh,  Xl,  1024);
    conv_hilo<<<dim3(24 * 16), dim3(256), 0, stream>>>(w_qkv, Wqh, Wql, 1024);
    conv_hilo<<<dim3(8 * 16),  dim3(256), 0, stream>>>(w_o,   Woh, Wol, 1024);

    // QKV projection with fused Q/K/V epilogue (512-thread blocks)
    hgemm_split<1><<<dim3(32 * 24), dim3(512), 0, stream>>>(
        Xh, Xl, Wqh, Wql, b_qkv, nullptr, Qarr, Kh, Kl, Vh, Vl, 32, 24, 16, 3072);
    attn_mfma<<<dim3(512), dim3(256), 0, stream>>>(Qarr, mask, Kh, Kl, Vh, Vl, Avh, Avl);
    // out projection
    hgemm_split<0><<<dim3(32 * 8), dim3(512), 0, stream>>>(
        Avh, Avl, Woh, Wol, b_o, out, nullptr, nullptr, nullptr, nullptr, nullptr,
        32, 8, 16, 1024);
}

// Round 9
// 300.815 us; speedup vs baseline: 3.3661x; 1.0622x over previous
//
#include <hip/hip_runtime.h>
#include <cmath>

#define B_  2
#define S_  2048
#define H_  1024
#define NH_ 16
#define HD_ 64

typedef _Float16 half8  __attribute__((ext_vector_type(8)));
typedef __fp16   fp16x2 __attribute__((ext_vector_type(2)));
typedef float    f32x16 __attribute__((ext_vector_type(16)));

#define MFMA32(a, b, c) __builtin_amdgcn_mfma_f32_32x32x16_f16((a), (b), (c), 0, 0, 0)

__device__ __forceinline__ void gl2lds16(const void* g, void* l) {
    __builtin_amdgcn_global_load_lds(
        (const __attribute__((address_space(1))) unsigned int*)g,
        (__attribute__((address_space(3))) unsigned int*)l,
        16, 0, 0);
}

__device__ __forceinline__ unsigned pk16(float a, float b) {
    union { fp16x2 v; unsigned u; } c;
    c.v = __builtin_amdgcn_cvt_pkrtz(a, b);
    return c.u;
}

// hardware 2^x
__device__ __forceinline__ float exp2_hw(float x) {
#if __has_builtin(__builtin_amdgcn_exp2f)
    return __builtin_amdgcn_exp2f(x);
#else
    return __expf(x * 0.6931471805599453f);
#endif
}

#define LOG2E   1.4426950408889634f
#define SCALE_  (0.125f * LOG2E)      // 1/sqrt(64) * log2(e)
#define THR2_   11.5415603f           // 8 * log2(e)

// GEMM operand tiles: 128 rows x 32 k halfs (4096 halfs / 8KB per plane).
// elem (r, g*8+e), g in 0..3, stored at r*32 + ((g ^ ((r>>1)&3))*8 + e).
#define GSWZ(r, g) (((g) ^ (((r) >> 1) & 3)) << 3)

// ---------------------------------------------------------------------------
// conv_hilo: src fp32 [R][K] -> hi/lo fp16 in 128x32 tiled-swizzled layout.
// One block per tile; bid = rt*(K/32) + ktc.
// ---------------------------------------------------------------------------
__global__ __launch_bounds__(256, 4)
void conv_hilo(const float* __restrict__ src, _Float16* __restrict__ dh,
               _Float16* __restrict__ dl, int K)
{
    const int bid = blockIdx.x;
    const int nkt = K >> 5;
    const int rt  = bid / nkt;
    const int ktc = bid % nkt;
    const int tid = threadIdx.x;
    const size_t tb = (size_t)bid * 4096;
#pragma unroll
    for (int p = 0; p < 2; ++p) {
        const int idx = p * 256 + tid;   // 0..511
        const int r   = idx >> 2;        // 0..127
        const int g   = idx & 3;         // 0..3
        const float* s = src + (size_t)(rt * 128 + r) * K + ktc * 32 + g * 8;
        const float4 v0 = *reinterpret_cast<const float4*>(s);
        const float4 v1 = *reinterpret_cast<const float4*>(s + 4);
        const float f[8] = {v0.x, v0.y, v0.z, v0.w, v1.x, v1.y, v1.z, v1.w};
        half8 hi, lo;
#pragma unroll
        for (int e = 0; e < 8; ++e) {
            const _Float16 hv = (_Float16)f[e];
            hi[e] = hv;
            lo[e] = (_Float16)(f[e] - (float)hv);
        }
        const int dst = r * 32 + GSWZ(r, g);
        *reinterpret_cast<half8*>(dh + tb + dst) = hi;
        *reinterpret_cast<half8*>(dl + tb + dst) = lo;
    }
}

// ---------------------------------------------------------------------------
// Split-fp16 MFMA GEMM: 128x128 tile, BK=32, 4 waves (2x2 of 64x64), 256 thr,
// double-buffered 2x32KB LDS -> 2 blocks/CU (2 waves/SIMD).
// QKV=0: C[m][n] = acc + bias (fp32).  QKV=1: fused epilogue writing
//   n<1024  -> Q fp32 [4096][1024]
//   n<2048  -> K hi/lo attention tiles (64x64: key*64 + (d ^ ((key&7)<<3)))
//   else    -> V^T hi/lo attention tiles (d*64 + (key ^ ((d&7)<<3)))
// ---------------------------------------------------------------------------
template<int QKV>
__global__ __launch_bounds__(256, 2)
void hgemm_split(const _Float16* __restrict__ Ah, const _Float16* __restrict__ Al,
                 const _Float16* __restrict__ Wh, const _Float16* __restrict__ Wl,
                 const float* __restrict__ bias, float* __restrict__ C,
                 float* __restrict__ Qo,
                 _Float16* __restrict__ Kh, _Float16* __restrict__ Kl,
                 _Float16* __restrict__ Vh, _Float16* __restrict__ Vl,
                 int nbm, int nbn, int nkt, int N)
{
    __shared__ __align__(16) unsigned char smem[65536];   // 2 x 32KB buffers
    // per buffer: Ah @0, Al @8192, Wh @16384, Wl @24576 (bytes)

    const int tid  = threadIdx.x;
    const int w    = tid >> 6;        // 0..3
    const int lane = tid & 63;
    const int lr   = lane & 31;
    const int hh   = lane >> 5;
    const int wm   = w >> 1;          // 0..1 : 64-row strip
    const int wn   = w & 1;           // 0..1 : 64-col half

    const int nwg = nbm * nbn;
    const int cpx = nwg >> 3;
    const int bid = blockIdx.x;
    const int wg  = (bid & 7) * cpx + (bid >> 3);
    const int mt  = wg / nbn, nt = wg % nbn;

    const size_t aBase = (size_t)mt * nkt * 4096;
    const size_t wBase = (size_t)nt * nkt * 4096;

    f32x16 acc[2][2];
#pragma unroll
    for (int mi = 0; mi < 2; ++mi)
#pragma unroll
        for (int ni = 0; ni < 2; ++ni)
#pragma unroll
            for (int r = 0; r < 16; ++r) acc[mi][ni][r] = 0.f;

    // staging: 8 gl2lds16 per thread into buffer `buf`
    auto stage = [&](int kt, int buf) {
        const size_t at = aBase + (size_t)kt * 4096;
        const size_t wt = wBase + (size_t)kt * 4096;
        unsigned char* sb = smem + (buf << 15);
#pragma unroll
        for (int c = 0; c < 2; ++c) {
            const int off = (c * 256 + tid) * 8;         // halfs, linear
            gl2lds16((const void*)(Ah + at + off), (void*)((_Float16*)sb + off));
            gl2lds16((const void*)(Al + at + off), (void*)((_Float16*)(sb + 8192) + off));
            gl2lds16((const void*)(Wh + wt + off), (void*)((_Float16*)(sb + 16384) + off));
            gl2lds16((const void*)(Wl + wt + off), (void*)((_Float16*)(sb + 24576) + off));
        }
    };

    stage(0, 0);
    __syncthreads();

    for (int kt = 0; kt < nkt; ++kt) {
        if (kt + 1 < nkt) stage(kt + 1, (kt + 1) & 1);

        unsigned char* sb = smem + ((kt & 1) << 15);
        _Float16* sAh = (_Float16*)(sb);
        _Float16* sAl = (_Float16*)(sb + 8192);
        _Float16* sWh = (_Float16*)(sb + 16384);
        _Float16* sWl = (_Float16*)(sb + 24576);

#pragma unroll
        for (int ks = 0; ks < 2; ++ks) {
            const int g = ks * 2 + hh;
            half8 aH[2], aL[2], bH[2], bL[2];
#pragma unroll
            for (int mi = 0; mi < 2; ++mi) {
                const int r   = wm * 64 + mi * 32 + lr;
                const int idx = r * 32 + GSWZ(r, g);
                aH[mi] = *reinterpret_cast<const half8*>(sAh + idx);
                aL[mi] = *reinterpret_cast<const half8*>(sAl + idx);
            }
#pragma unroll
            for (int ni = 0; ni < 2; ++ni) {
                const int c   = wn * 64 + ni * 32 + lr;
                const int idx = c * 32 + GSWZ(c, g);
                bH[ni] = *reinterpret_cast<const half8*>(sWh + idx);
                bL[ni] = *reinterpret_cast<const half8*>(sWl + idx);
            }
            __builtin_amdgcn_s_setprio(1);
#pragma unroll
            for (int mi = 0; mi < 2; ++mi)
#pragma unroll
                for (int ni = 0; ni < 2; ++ni) {
                    acc[mi][ni] = MFMA32(aH[mi], bH[ni], acc[mi][ni]);
                    acc[mi][ni] = MFMA32(aH[mi], bL[ni], acc[mi][ni]);
                    acc[mi][ni] = MFMA32(aL[mi], bH[ni], acc[mi][ni]);
                }
            __builtin_amdgcn_s_setprio(0);
        }
        __syncthreads();   // joins waves AND drains the kt+1 prefetch
    }

    if constexpr (QKV == 0) {
        const int n0 = nt * 128 + wn * 64 + lr;
        float bv[2];
#pragma unroll
        for (int ni = 0; ni < 2; ++ni) bv[ni] = bias[n0 + ni * 32];
#pragma unroll
        for (int mi = 0; mi < 2; ++mi)
#pragma unroll
            for (int ni = 0; ni < 2; ++ni)
#pragma unroll
                for (int r = 0; r < 16; ++r) {
                    const int m = mt * 128 + wm * 64 + mi * 32 +
                                  (r & 3) + 8 * (r >> 2) + 4 * hh;
                    C[(size_t)m * N + n0 + ni * 32] = acc[mi][ni][r] + bv[ni];
                }
    } else {
        // fused QKV epilogue through LDS (two 64-row passes); all compute done
        // (final barrier above), so aliasing smem is safe.
        float* sC = (float*)smem;                     // [64][132]
        const int m0  = mt * 128;
        const int b   = m0 >> 11;
        const int kt0 = (m0 & 2047) >> 6;             // attn 64-row K/V tile idx
#pragma unroll
        for (int pass = 0; pass < 2; ++pass) {
            __syncthreads();
            if (wm == pass) {
#pragma unroll
                for (int mi = 0; mi < 2; ++mi)
#pragma unroll
                    for (int ni = 0; ni < 2; ++ni)
#pragma unroll
                        for (int r = 0; r < 16; ++r) {
                            const int ml = mi * 32 + (r & 3) + 8 * (r >> 2) + 4 * hh;
                            sC[ml * 132 + wn * 64 + ni * 32 + lr] = acc[mi][ni][r];
                        }
            }
            __syncthreads();
            const int ktile = kt0 + pass;
            if (nt < 8) {
                // Q region: fp32, coalesced
#pragma unroll
                for (int it = 0; it < 8; ++it) {
                    const int idx = it * 256 + tid;
                    const int row = idx >> 5;
                    const int c4  = (idx & 31) << 2;
                    float4 v = *reinterpret_cast<const float4*>(&sC[row * 132 + c4]);
                    const float4 bv = *reinterpret_cast<const float4*>(bias + nt * 128 + c4);
                    v.x += bv.x; v.y += bv.y; v.z += bv.z; v.w += bv.w;
                    *reinterpret_cast<float4*>(
                        Qo + (size_t)(m0 + pass * 64 + row) * 1024 + nt * 128 + c4) = v;
                }
            } else if (nt < 16) {
                // K region: hi/lo attn tiles (64x64 swizzled)
#pragma unroll
                for (int it = 0; it < 4; ++it) {
                    const int idx = it * 256 + tid;
                    const int key = idx >> 4;
                    const int g   = idx & 15;
                    const int head = 2 * (nt - 8) + (g >> 3);
                    const int d0   = (g & 7) << 3;
                    float f[8];
#pragma unroll
                    for (int e = 0; e < 8; ++e)
                        f[e] = sC[key * 132 + g * 8 + e] +
                               bias[1024 + (nt - 8) * 128 + g * 8 + e];
                    half8 hi, lo;
#pragma unroll
                    for (int e = 0; e < 8; ++e) {
                        const _Float16 hv = (_Float16)f[e];
                        hi[e] = hv;
                        lo[e] = (_Float16)(f[e] - (float)hv);
                    }
                    const size_t base = ((size_t)(b * 16 + head) * 32 + ktile) * 4096;
                    const size_t dst  = base + key * 64 + (d0 ^ ((key & 7) << 3));
                    *reinterpret_cast<half8*>(Kh + dst) = hi;
                    *reinterpret_cast<half8*>(Kl + dst) = lo;
                }
            } else {
                // V region: transposed hi/lo attn tiles
#pragma unroll
                for (int it = 0; it < 4; ++it) {
                    const int idx = it * 256 + tid;
                    const int f   = idx >> 3;        // feature col 0..127
                    const int kg  = idx & 7;         // key-group
                    const int head = 2 * (nt - 16) + (f >> 6);
                    const int d    = f & 63;
                    const float bv = bias[2048 + (nt - 16) * 128 + f];
                    float fe[8];
#pragma unroll
                    for (int e = 0; e < 8; ++e)
                        fe[e] = sC[(kg * 8 + e) * 132 + f] + bv;
                    half8 hi, lo;
#pragma unroll
                    for (int e = 0; e < 8; ++e) {
                        const _Float16 hv = (_Float16)fe[e];
                        hi[e] = hv;
                        lo[e] = (_Float16)(fe[e] - (float)hv);
                    }
                    const size_t base = ((size_t)(b * 16 + head) * 32 + ktile) * 4096;
                    const size_t dst  = base + d * 64 + ((kg * 8) ^ ((d & 7) << 3));
                    *reinterpret_cast<half8*>(Vh + dst) = hi;
                    *reinterpret_cast<half8*>(Vl + dst) = lo;
                }
            }
        }
    }
}

// ---------------------------------------------------------------------------
// Flash attention, split-fp16 MFMA, swapped-QK, double-buffered staging.
// QK^T: 3-term split. PV: 2-term (Pl dropped; error < 2e-4). log2-domain SM.
// Av emitted directly in the GEMM 128x32 tiled operand layout.
// ---------------------------------------------------------------------------
__global__ __launch_bounds__(256, 2)
void attn_mfma(const float* __restrict__ Q, const float* __restrict__ mask,
               const _Float16* __restrict__ Kh, const _Float16* __restrict__ Kl,
               const _Float16* __restrict__ Vh, const _Float16* __restrict__ Vl,
               _Float16* __restrict__ Avh, _Float16* __restrict__ Avl)
{
    __shared__ __align__(16) unsigned char smem[73728];
    // buf0 @0, buf1 @32768; within buf: Kh 0, Kl +4096, Vh +8192, Vl +12288 (halfs)
    float* sM = (float*)(smem + 65536);
    float* sO = (float*)(smem);        // epilogue alias [128][68]

    const int tid  = threadIdx.x;
    const int w    = tid >> 6;
    const int lane = tid & 63;
    const int lq   = lane & 31;
    const int hh   = lane >> 5;

    const int bid = blockIdx.x;
    const int wg  = (bid & 7) * 64 + (bid >> 3);
    const int bh  = wg >> 4;
    const int qb  = wg & 15;
    const int b   = bh >> 4, h = bh & 15;

    // mask * log2e/8 -> LDS
    {
        const float4* mg = reinterpret_cast<const float4*>(mask);
        float4* ms = reinterpret_cast<float4*>(sM);
        float4 a = mg[tid], c = mg[tid + 256];
        a.x *= SCALE_; a.y *= SCALE_; a.z *= SCALE_; a.w *= SCALE_;
        c.x *= SCALE_; c.y *= SCALE_; c.z *= SCALE_; c.w *= SCALE_;
        ms[tid] = a; ms[tid + 256] = c;
    }

    // Q fragments scaled by log2e/8, fp16 split
    const int qrow = b * S_ + qb * 128 + w * 32 + lq;
    half8 qh[4], ql[4];
#pragma unroll
    for (int ks = 0; ks < 4; ++ks) {
        const float* qp = Q + (size_t)qrow * 1024 + h * HD_ + ks * 16 + hh * 8;
        const float4 a = *reinterpret_cast<const float4*>(qp);
        const float4 c = *reinterpret_cast<const float4*>(qp + 4);
        float qf[8] = {a.x, a.y, a.z, a.w, c.x, c.y, c.z, c.w};
#pragma unroll
        for (int e = 0; e < 8; ++e) {
            const float sv = qf[e] * SCALE_;
            const _Float16 hv = (_Float16)sv;
            qh[ks][e] = hv;
            ql[ks][e] = (_Float16)(sv - (float)hv);
        }
    }

    // loop-invariant swizzled LDS offsets (shared by K and V^T reads)
    const int swz = (lq & 7) << 3;
    int off[2][4];
#pragma unroll
    for (int t2 = 0; t2 < 2; ++t2)
#pragma unroll
        for (int ks = 0; ks < 4; ++ks)
            off[t2][ks] = (t2 * 32 + lq) * 64 + ((ks * 16 + hh * 8) ^ swz);

    f32x16 o0 = {0,0,0,0,0,0,0,0,0,0,0,0,0,0,0,0};
    f32x16 o1 = {0,0,0,0,0,0,0,0,0,0,0,0,0,0,0,0};
    float m_run = -INFINITY, l_run = 0.f;

    const size_t bhbase = (size_t)bh * 32 * 4096;

    // prologue: stage tile 0 into buf0
    {
        const size_t tb = bhbase;
#pragma unroll
        for (int i = 0; i < 2; ++i) {
            const int loff = (w * 2 + i) * 512;
            const int goff = loff + lane * 8;
            _Float16* nb = (_Float16*)smem;
            gl2lds16((const void*)(Kh + tb + goff), (void*)(nb + loff));
            gl2lds16((const void*)(Kl + tb + goff), (void*)(nb + 4096 + loff));
            gl2lds16((const void*)(Vh + tb + goff), (void*)(nb + 8192 + loff));
            gl2lds16((const void*)(Vl + tb + goff), (void*)(nb + 12288 + loff));
        }
    }
    __syncthreads();

    for (int kt = 0; kt < 32; ++kt) {
        _Float16* bb = (_Float16*)(smem + ((kt & 1) << 15));
        // prefetch next tile into the other buffer
        if (kt < 31) {
            _Float16* nb = (_Float16*)(smem + (((kt + 1) & 1) << 15));
            const size_t tb = bhbase + (size_t)(kt + 1) * 4096;
#pragma unroll
            for (int i = 0; i < 2; ++i) {
                const int loff = (w * 2 + i) * 512;
                const int goff = loff + lane * 8;
                gl2lds16((const void*)(Kh + tb + goff), (void*)(nb + loff));
                gl2lds16((const void*)(Kl + tb + goff), (void*)(nb + 4096 + loff));
                gl2lds16((const void*)(Vh + tb + goff), (void*)(nb + 8192 + loff));
                gl2lds16((const void*)(Vl + tb + goff), (void*)(nb + 12288 + loff));
            }
        }

        // ---- S^T = K Q^T (3-term split) ----
        f32x16 st[2];
#pragma unroll
        for (int ktt = 0; ktt < 2; ++ktt) {
            f32x16 acc = {0,0,0,0,0,0,0,0,0,0,0,0,0,0,0,0};
            __builtin_amdgcn_s_setprio(1);
#pragma unroll
            for (int ks = 0; ks < 4; ++ks) {
                const half8 ka = *reinterpret_cast<const half8*>(bb + off[ktt][ks]);
                const half8 kb = *reinterpret_cast<const half8*>(bb + 4096 + off[ktt][ks]);
                acc = MFMA32(ka, qh[ks], acc);
                acc = MFMA32(ka, ql[ks], acc);
                acc = MFMA32(kb, qh[ks], acc);
            }
            __builtin_amdgcn_s_setprio(0);
            st[ktt] = acc;
        }

        // ---- + mask (pre-scaled), running max (log2 units) ----
        float mx = -INFINITY;
#pragma unroll
        for (int ktt = 0; ktt < 2; ++ktt) {
#pragma unroll
            for (int rr = 0; rr < 4; ++rr) {
                const int key0 = kt * 64 + ktt * 32 + rr * 8 + hh * 4;
                const float4 mk = *reinterpret_cast<const float4*>(sM + key0);
                const float mkv[4] = {mk.x, mk.y, mk.z, mk.w};
#pragma unroll
                for (int c = 0; c < 4; ++c) {
                    const int r = rr * 4 + c;
                    const float tv = st[ktt][r] + mkv[c];
                    st[ktt][r] = tv;
                    mx = fmaxf(mx, tv);
                }
            }
        }
        mx = fmaxf(mx, __shfl_xor(mx, 32));

        // ---- defer-max online softmax (T13) ----
        if (!__all(mx - m_run <= THR2_)) {
            const float mnew = fmaxf(m_run, mx);
            const float corr = exp2_hw(m_run - mnew);
            m_run = mnew;
            l_run *= corr;
#pragma unroll
            for (int r = 0; r < 16; ++r) { o0[r] *= corr; o1[r] *= corr; }
        }
        float ps = 0.f;
#pragma unroll
        for (int ktt = 0; ktt < 2; ++ktt)
#pragma unroll
            for (int r = 0; r < 16; ++r) {
                const float p = exp2_hw(st[ktt][r] - m_run);
                st[ktt][r] = p;
                ps += p;
            }
        ps += __shfl_xor(ps, 32);
        l_run += ps;

        // ---- pack P hi via pkrtz ----
        unsigned wph[2][4][2];
#pragma unroll
        for (int ktt = 0; ktt < 2; ++ktt)
#pragma unroll
            for (int rr = 0; rr < 4; ++rr)
#pragma unroll
                for (int pp = 0; pp < 2; ++pp)
                    wph[ktt][rr][pp] = pk16(st[ktt][rr * 4 + pp * 2 + 0],
                                            st[ktt][rr * 4 + pp * 2 + 1]);

        // ---- assemble P B-frags via shfl_xor(32); O^T += V^T P^T (2-term) ----
#pragma unroll
        for (int ks = 0; ks < 4; ++ks) {
            const int i1 = ks >> 1;
            const int rA = (ks & 1) * 2;
            union { unsigned u[4]; half8 v; } ph;
            {
                const unsigned oA0 = wph[i1][rA + 0][0], oB0 = wph[i1][rA + 0][1];
                const unsigned oA1 = wph[i1][rA + 1][0], oB1 = wph[i1][rA + 1][1];
                const unsigned sA1 = (unsigned)__shfl_xor((int)oA1, 32);
                const unsigned sB1 = (unsigned)__shfl_xor((int)oB1, 32);
                const unsigned sA0 = (unsigned)__shfl_xor((int)oA0, 32);
                const unsigned sB0 = (unsigned)__shfl_xor((int)oB0, 32);
                ph.u[0] = hh ? sA1 : oA0;
                ph.u[1] = hh ? sB1 : oB0;
                ph.u[2] = hh ? oA1 : sA0;
                ph.u[3] = hh ? oB1 : sB0;
            }
            __builtin_amdgcn_s_setprio(1);
#pragma unroll
            for (int dt = 0; dt < 2; ++dt) {
                const half8 va = *reinterpret_cast<const half8*>(bb + 8192 + off[dt][ks]);
                const half8 vb = *reinterpret_cast<const half8*>(bb + 12288 + off[dt][ks]);
                if (dt == 0) {
                    o0 = MFMA32(va, ph.v, o0);
                    o0 = MFMA32(vb, ph.v, o0);
                } else {
                    o1 = MFMA32(va, ph.v, o1);
                    o1 = MFMA32(vb, ph.v, o1);
                }
            }
            __builtin_amdgcn_s_setprio(0);
        }
        __syncthreads();   // joins waves AND drains the kt+1 prefetch
    }

    // ---- epilogue: normalize, LDS transpose, emit GEMM-tiled hi/lo Av ----
    const float inv = 1.f / l_run;
#pragma unroll
    for (int dt = 0; dt < 2; ++dt)
#pragma unroll
        for (int r = 0; r < 16; ++r) {
            const int d = dt * 32 + (r & 3) + 8 * (r >> 2) + 4 * hh;
            sO[(w * 32 + lq) * 68 + d] = (dt ? o1[r] : o0[r]) * inv;
        }
    __syncthreads();
    {
        // A-operand tiles: mt = b*16+qb, k-tiles h*2 + {0,1}
        const size_t tbase = (((size_t)(b * 16 + qb)) * 32 + h * 2) * 4096;
#pragma unroll
        for (int p = 0; p < 4; ++p) {
            const int idx = p * 256 + tid;
            const int q = idx >> 3, g = idx & 7;     // g: 8 groups of 8 cols
            const float4 v0 = *reinterpret_cast<const float4*>(&sO[q * 68 + g * 8]);
            const float4 v1 = *reinterpret_cast<const float4*>(&sO[q * 68 + g * 8 + 4]);
            const float f[8] = {v0.x, v0.y, v0.z, v0.w, v1.x, v1.y, v1.z, v1.w};
            half8 hi, lo;
#pragma unroll
            for (int e = 0; e < 8; ++e) {
                const _Float16 hv = (_Float16)f[e];
                hi[e] = hv;
                lo[e] = (_Float16)(f[e] - (float)hv);
            }
            const int th = g >> 2, g2 = g & 3;
            const size_t dst = tbase + th * 4096 + q * 32 + GSWZ(q, g2);
            *reinterpret_cast<half8*>(Avh + dst) = hi;
            *reinterpret_cast<half8*>(Avl + dst) = lo;
        }
    }
}

// ---------------------------------------------------------------------------
extern "C" void kernel_launch(void* const* d_in, const int* in_sizes, int n_in,
                              void* d_out, int out_size, void* d_ws, size_t ws_size,
                              hipStream_t stream)
{
    const float* x     = (const float*)d_in[0];
    const float* mask  = (const float*)d_in[1];
    const float* w_qkv = (const float*)d_in[2];
    const float* b_qkv = (const float*)d_in[3];
    const float* w_o   = (const float*)d_in[4];
    const float* b_o   = (const float*)d_in[5];
    float* out = (float*)d_out;

    char* p = (char*)d_ws;
    float*    Qarr = (float*)p;             p += (size_t)4096 * 1024 * 4;      // 16 MB
    _Float16* Kh   = (_Float16*)p;          p += (size_t)32 * 32 * 4096 * 2;   // 8 MB each
    _Float16* Kl   = (_Float16*)p;          p += (size_t)32 * 32 * 4096 * 2;
    _Float16* Vh   = (_Float16*)p;          p += (size_t)32 * 32 * 4096 * 2;
    _Float16* Vl   = (_Float16*)p;          p += (size_t)32 * 32 * 4096 * 2;
    _Float16* Xh   = (_Float16*)p;          p += (size_t)4096 * 1024 * 2;
    _Float16* Xl   = (_Float16*)p;          p += (size_t)4096 * 1024 * 2;
    _Float16* Wqh  = (_Float16*)p;          p += (size_t)3072 * 1024 * 2;
    _Float16* Wql  = (_Float16*)p;          p += (size_t)3072 * 1024 * 2;
    _Float16* Woh  = (_Float16*)p;          p += (size_t)1024 * 1024 * 2;
    _Float16* Wol  = (_Float16*)p;          p += (size_t)1024 * 1024 * 2;
    _Float16* Avh  = (_Float16*)p;          p += (size_t)4096 * 1024 * 2;
    _Float16* Avl  = (_Float16*)p;          p += (size_t)4096 * 1024 * 2;

    conv_hilo<<<dim3(32 * 32), dim3(256), 0, stream>>>(x,     Xh,  Xl,  1024);
    conv_hilo<<<dim3(24 * 32), dim3(256), 0, stream>>>(w_qkv, Wqh, Wql, 1024);
    conv_hilo<<<dim3(8 * 32),  dim3(256), 0, stream>>>(w_o,   Woh, Wol, 1024);

    // QKV projection with fused Q/K/V epilogue: nkt = 1024/32 = 32
    hgemm_split<1><<<dim3(32 * 24), dim3(256), 0, stream>>>(
        Xh, Xl, Wqh, Wql, b_qkv, nullptr, Qarr, Kh, Kl, Vh, Vl, 32, 24, 32, 3072);
    attn_mfma<<<dim3(512), dim3(256), 0, stream>>>(Qarr, mask, Kh, Kl, Vh, Vl, Avh, Avl);
    // out projection
    hgemm_split<0><<<dim3(32 * 8), dim3(256), 0, stream>>>(
        Avh, Avl, Woh, Wol, b_o, out, nullptr, nullptr, nullptr, nullptr, nullptr,
        32, 8, 32, 1024);
}